// Round 10
// baseline (938.944 us; speedup 1.0000x reference)
//
#include <hip/hip_runtime.h>
#include <hip/hip_bf16.h>
#include <hip/hip_cooperative_groups.h>

namespace cg = cooperative_groups;

typedef unsigned short u16;
typedef unsigned int   u32;
typedef __attribute__((ext_vector_type(8))) short bf16x8;   // 8 bf16 = 4 VGPRs
typedef __attribute__((ext_vector_type(4))) float f32x4;

// ---------- helpers ----------
__device__ __forceinline__ float bf2f(u16 u) {
    union { u32 i; float f; } v; v.i = ((u32)u) << 16; return v.f;
}
__device__ __forceinline__ u16 f2bf(float f) {
    __hip_bfloat16 h = __float2bfloat16(f);
    return *reinterpret_cast<u16*>(&h);
}
__device__ __forceinline__ float sigm(float x) { return 1.0f / (1.0f + expf(-x)); }

#define PAD_IDX 100000

// ---------- workspace-too-small sentinel ----------
__global__ __launch_bounds__(256)
void signal_fail(float* out) {
    int i = blockIdx.x * 256 + threadIdx.x;
    if (i < 4096) out[i] = 12345.0f;
}

// ---------- f32 -> bf16 conversion ----------
// (R9 lesson: harness re-poisons the workspace between iterations — dispatch-ID
// count shows ~25 reset memsets/iter — so weight prep CANNOT be cached; runs
// every iteration.)
__global__ __launch_bounds__(256)
void conv_bf16(const float* __restrict__ in, u16* __restrict__ out, long n) {
    long i = ((long)blockIdx.x * 256 + threadIdx.x) * 4;
    const long stride = (long)gridDim.x * 256 * 4;
    for (; i < n; i += stride) {
        float4 v = *(const float4*)(in + i);
        u16 o[4] = { f2bf(v.x), f2bf(v.y), f2bf(v.z), f2bf(v.w) };
        *(uint2*)(out + i) = *(uint2*)o;
    }
}

// ---------- fused small-weight conversions (projw | sew1 | sew2) ----------
__global__ __launch_bounds__(256)
void conv3_bf16(const float* __restrict__ projw, u16* __restrict__ projwb,
                const float* __restrict__ sew1, u16* __restrict__ sew1b,
                const float* __restrict__ sew2, u16* __restrict__ sew2b)
{
    const float* in; u16* out; long n, b0;
    const int bx = blockIdx.x;
    if (bx < 64)        { in = projw; out = projwb; n = 65536;  b0 = bx; }
    else if (bx < 576)  { in = sew1;  out = sew1b;  n = 524288; b0 = bx - 64; }
    else                { in = sew2;  out = sew2b;  n = 524288; b0 = bx - 576; }
    long i = (b0 * 256 + threadIdx.x) * 4;
    if (i < n) {
        float4 v = *(const float4*)(in + i);
        u16 o[4] = { f2bf(v.x), f2bf(v.y), f2bf(v.z), f2bf(v.w) };
        *(uint2*)(out + i) = *(uint2*)o;
    }
}

// ---------- Part A: neighbor encoder (R6-exact: one side per block) ----------
// Merged grid: blocks [0,8192) = query (side = bid>>12, b = bid&4095),
// blocks [8192,8202) = support. BF16E: full-batch 26-load gather per wave.
// Measured best: 205us. The gather pattern (random 512B rows of a 51MB table)
// plateaus at ~4 TB/s demand regardless of occupancy; R7's forced-occupancy
// attempt spilled (VGPR 32, 965MB scratch) and regressed 2.4x. Do NOT add
// __launch_bounds__ min-wave hints: natural VGPR is ~88.
template<bool BF16E>
__global__ __launch_bounds__(256)
void neighbor_mfma(const int* __restrict__ q_l1, const int* __restrict__ q_r1,
                   const int* __restrict__ s_l1, const int* __restrict__ s_r1,
                   const int* __restrict__ query, const int* __restrict__ support,
                   const float* __restrict__ emb, const u16* __restrict__ embb,
                   const u16* __restrict__ projw_b,
                   const float* __restrict__ projlb, const float* __restrict__ projb,
                   const float* __restrict__ gatew, const float* __restrict__ gatelb,
                   const float* __restrict__ gateb,
                   u16* __restrict__ outX)
{
    __shared__ u16   nvA[64][264];     // [k-row][d], pad 256->264
    __shared__ __align__(8) int sconn[100];
    __shared__ float maskv[64];
    __shared__ float sagg[256];
    __shared__ float sred4[4];
    __shared__ float scnt;

    const int bid = blockIdx.x;
    const int* __restrict__ conn;
    const int* __restrict__ sel;
    int b, side, row_off;
    if (bid < 8192) {
        side = bid >> 12; b = bid & 4095;
        conn = side ? q_r1 : q_l1; sel = query; row_off = 0;
    } else {
        const int i = bid - 8192;
        side = i / 5; b = i - side * 5;
        conn = side ? s_r1 : s_l1; sel = support; row_off = 4096;
    }
    const int col_off = side * 256;

    const int t = threadIdx.x;
    const int w = t >> 6, lane = t & 63, quad = lane >> 4, cc = lane & 15;

    if (t < 100) sconn[t] = conn[b * 100 + t];
    const int sid = sel[b * 2 + side];
    const float selfv = emb[(size_t)sid * 256 + t];   // f32 self row (accuracy)
    __syncthreads();

    if (BF16E) {
        // ---- full-batch prefetch: wave w owns k = w + 4*kk ----
        const int nslots = (w < 2) ? 13 : 12;          // wave-uniform
        uint2 ra[13], re[13];
#pragma unroll
        for (int kk = 0; kk < 13; kk++) {
            if (kk < nslots) {
                const int k = w + kk * 4;
                const int2 id = *(const int2*)&sconn[2 * k];
                ra[kk] = *(const uint2*)(embb + (size_t)id.x * 256 + lane * 4);
                re[kk] = *(const uint2*)(embb + (size_t)id.y * 256 + lane * 4);
            }
        }
        // independent work hides under the in-flight loads
        float cnt = 0.f;
        for (int k = 0; k < 50; k++) if (sconn[2 * k] != PAD_IDX) cnt += 1.f;
        if (t < 64) maskv[t] = (t < 50 && sconn[2 * t] != PAD_IDX) ? 1.f : 0.f;
        for (int k = 50; k < 64; k++) nvA[k][t] = 0;
        if (t == 0) scnt = cnt;

#pragma unroll
        for (int kk = 0; kk < 13; kk++) {
            if (kk < nslots) {
                const int k = w + kk * 4;
                u16 o[4];
                o[0] = f2bf(bf2f((u16)(ra[kk].x & 0xffff)) * bf2f((u16)(re[kk].x & 0xffff)));
                o[1] = f2bf(bf2f((u16)(ra[kk].x >> 16))    * bf2f((u16)(re[kk].x >> 16)));
                o[2] = f2bf(bf2f((u16)(ra[kk].y & 0xffff)) * bf2f((u16)(re[kk].y & 0xffff)));
                o[3] = f2bf(bf2f((u16)(ra[kk].y >> 16))    * bf2f((u16)(re[kk].y >> 16)));
                *(uint2*)&nvA[k][lane * 4] = *(uint2*)o;
            }
        }
    } else {
        // f32 fallback: float4 rows, 1-deep prefetch
        float cnt = 0.f;
        for (int k = 0; k < 50; k++) if (sconn[2 * k] != PAD_IDX) cnt += 1.f;
        if (t < 64) maskv[t] = (t < 50 && sconn[2 * t] != PAD_IDX) ? 1.f : 0.f;
        for (int k = 50; k < 64; k++) nvA[k][t] = 0;
        if (t == 0) scnt = cnt;

        int k = w;
        float4 rra, rre;
        {
            const int rel = sconn[2 * k], ent = sconn[2 * k + 1];
            rra = *(const float4*)(emb + (size_t)rel * 256 + lane * 4);
            rre = *(const float4*)(emb + (size_t)ent * 256 + lane * 4);
        }
        while (true) {
            const int kn = k + 4;
            float4 na, ne;
            if (kn < 50) {
                const int rel = sconn[2 * kn], ent = sconn[2 * kn + 1];
                na = *(const float4*)(emb + (size_t)rel * 256 + lane * 4);
                ne = *(const float4*)(emb + (size_t)ent * 256 + lane * 4);
            }
            u16 o[4] = { f2bf(rra.x * rre.x), f2bf(rra.y * rre.y),
                         f2bf(rra.z * rre.z), f2bf(rra.w * rre.w) };
            *(uint2*)&nvA[k][lane * 4] = *(uint2*)o;
            if (kn >= 50) break;
            rra = na; rre = ne; k = kn;
        }
    }
    __syncthreads();
    const float cnt = scnt;

    f32x4 acc[4][4];
#pragma unroll
    for (int mt = 0; mt < 4; mt++)
#pragma unroll
        for (int nt = 0; nt < 4; nt++) acc[mt][nt] = (f32x4){0.f, 0.f, 0.f, 0.f};

    for (int k0 = 0; k0 < 256; k0 += 32) {
        bf16x8 a[4];
#pragma unroll
        for (int mt = 0; mt < 4; mt++)
            a[mt] = *(const bf16x8*)&nvA[mt * 16 + cc][k0 + quad * 8];
#pragma unroll
        for (int nt = 0; nt < 4; nt++) {
            const int e = (w * 4 + nt) * 16 + cc;
            bf16x8 bv = *(const bf16x8*)(projw_b + (size_t)e * 256 + k0 + quad * 8);
#pragma unroll
            for (int mt = 0; mt < 4; mt++)
                acc[mt][nt] = __builtin_amdgcn_mfma_f32_16x16x32_bf16(a[mt], bv, acc[mt][nt], 0, 0, 0);
        }
    }

    float pbv[4], cs[4] = {0.f, 0.f, 0.f, 0.f};
#pragma unroll
    for (int nt = 0; nt < 4; nt++) {
        const int e = (w * 4 + nt) * 16 + cc;
        pbv[nt] = projlb[e] + projb[e];
    }
#pragma unroll
    for (int mt = 0; mt < 4; mt++)
#pragma unroll
        for (int r = 0; r < 4; r++) {
            const float mk = maskv[mt * 16 + quad * 4 + r];
#pragma unroll
            for (int nt = 0; nt < 4; nt++) {
                float v = acc[mt][nt][r] + pbv[nt];
                v = v > 0.f ? v : 0.01f * v;     // leaky_relu(0.01)
                cs[nt] += mk * v;
            }
        }
#pragma unroll
    for (int nt = 0; nt < 4; nt++) {
        cs[nt] += __shfl_xor(cs[nt], 16);
        cs[nt] += __shfl_xor(cs[nt], 32);
    }
    if (quad == 0) {
#pragma unroll
        for (int nt = 0; nt < 4; nt++) sagg[(w * 4 + nt) * 16 + cc] = cs[nt];
    }
    __syncthreads();

    const float agg = sagg[t] / (cnt + 1e-9f);
    // gate dot: wave shuffle reduce (2 barriers total)
    float gv = selfv * gatew[t] + agg * gatew[256 + t];
#pragma unroll
    for (int off = 32; off > 0; off >>= 1) gv += __shfl_xor(gv, off);
    if (lane == 0) sred4[w] = gv;
    __syncthreads();
    const float sgate = sigm(sred4[0] + sred4[1] + sred4[2] + sred4[3]
                             + gatelb[0] + gateb[0]);
    outX[(size_t)(row_off + b) * 512 + col_off + t] = f2bf(tanhf(selfv + sgate * agg));
}

// ---------- generic bf16 MFMA GEMM: C = act(A @ B^T + bias_f32 + resid_bf16) ----------
__global__ __launch_bounds__(256)
void gemm_bf16(const u16* __restrict__ A, int lda, const u16* __restrict__ B, int ldb,
               u16* __restrict__ C, int ldc, int M, int N, int K,
               const float* __restrict__ bias, const u16* __restrict__ resid, int ldr, int act)
{
    __shared__ u16 As[128][40];
    __shared__ u16 Bs[128][40];

    const int t = threadIdx.x;
    const int m0 = blockIdx.y * 128, n0 = blockIdx.x * 128;
    const int w = t >> 6, lane = t & 63, quad = lane >> 4, cc = lane & 15;
    const int wm = w >> 1, wn = w & 1;

    f32x4 acc[4][4];
#pragma unroll
    for (int mt = 0; mt < 4; mt++)
#pragma unroll
        for (int nt = 0; nt < 4; nt++) acc[mt][nt] = (f32x4){0.f, 0.f, 0.f, 0.f};

    for (int k0 = 0; k0 < K; k0 += 32) {
#pragma unroll
        for (int i = 0; i < 2; i++) {
            const int idx = t + i * 256;
            const int row = idx >> 2, seg = idx & 3;
            const int gm = m0 + row, gn = n0 + row;
            uint4 va = make_uint4(0, 0, 0, 0), vb = make_uint4(0, 0, 0, 0);
            if (gm < M) va = *(const uint4*)(A + (size_t)gm * lda + k0 + seg * 8);
            if (gn < N) vb = *(const uint4*)(B + (size_t)gn * ldb + k0 + seg * 8);
            *(uint4*)&As[row][seg * 8] = va;
            *(uint4*)&Bs[row][seg * 8] = vb;
        }
        __syncthreads();

        bf16x8 af[4], bfr[4];
#pragma unroll
        for (int mt = 0; mt < 4; mt++)
            af[mt] = *(const bf16x8*)&As[wm * 64 + mt * 16 + cc][quad * 8];
#pragma unroll
        for (int nt = 0; nt < 4; nt++)
            bfr[nt] = *(const bf16x8*)&Bs[wn * 64 + nt * 16 + cc][quad * 8];
#pragma unroll
        for (int mt = 0; mt < 4; mt++)
#pragma unroll
            for (int nt = 0; nt < 4; nt++)
                acc[mt][nt] = __builtin_amdgcn_mfma_f32_16x16x32_bf16(af[mt], bfr[nt], acc[mt][nt], 0, 0, 0);
        __syncthreads();
    }

#pragma unroll
    for (int mt = 0; mt < 4; mt++)
#pragma unroll
        for (int r = 0; r < 4; r++) {
            const int gm = m0 + wm * 64 + mt * 16 + quad * 4 + r;
            if (gm >= M) continue;
#pragma unroll
            for (int nt = 0; nt < 4; nt++) {
                const int gn = n0 + wn * 64 + nt * 16 + cc;
                if (gn >= N) continue;
                float x = acc[mt][nt][r];
                if (bias)  x += bias[gn];
                if (resid) x += bf2f(resid[(size_t)gm * ldr + gn]);
                if (act == 1) x = x > 0.f ? x : 0.f;
                C[(size_t)gm * ldc + gn] = f2bf(x);
            }
        }
}

// ---------- FUSED cooperative LSTM: all 4 steps + final dot in one kernel ----------
// grid (16,32) = 512 blocks = exactly 2 blocks/CU (LDS 20.5KB, VGPR<=256 via
// __launch_bounds__(256,2); natural ~200 so no spill). Per thread, held in
// registers across steps: g0 (ENC@Wih gate preacts, computed ONCE — kills the
// 3x recompute), cell state c, ENCb residual. grid.sync() + threadfence orders
// the h ping-pong. Accumulation order identical to the 4-launch path.
__global__ __launch_bounds__(256, 2)
void lstm_fused(const u16* __restrict__ ENCb, u16* __restrict__ hb0, u16* __restrict__ hb1,
                const u16* __restrict__ Wp, const float* __restrict__ fb0p,
                const float* __restrict__ fb1p, const float* __restrict__ sgv,
                float* __restrict__ outv)
{
    cg::grid_group grid = cg::this_grid();
    __shared__ u16 As[128][40];
    __shared__ u16 Bs[128][40];

    const int t = threadIdx.x;
    const int m0 = blockIdx.y * 128, n0 = blockIdx.x * 128;
    const int w = t >> 6, lane = t & 63, quad = lane >> 4, cc = lane & 15;
    const int wm = w >> 1, wn = w & 1;
    const int j = blockIdx.x * 32 + wn * 16 + cc;            // 0..511

    const float fb0i = fb0p[n0 + wn * 64 +  0 + cc];
    const float fb0f = fb0p[n0 + wn * 64 + 16 + cc];
    const float fb0g = fb0p[n0 + wn * 64 + 32 + cc];
    const float fb0o = fb0p[n0 + wn * 64 + 48 + cc];
    const float fb1i = fb1p[n0 + wn * 64 +  0 + cc];
    const float fb1f = fb1p[n0 + wn * 64 + 16 + cc];
    const float fb1g = fb1p[n0 + wn * 64 + 32 + cc];
    const float fb1o = fb1p[n0 + wn * 64 + 48 + cc];
    const float sgj  = sgv[j];

    f32x4 g0[4][4];           // ENC@Wih partials (kept across steps)
    float creg[4][4];         // cell state
    float encv[4][4];         // ENCb residual values

    // ================= step 1: K = 0..512, A = ENCb =================
    {
        f32x4 acc[4][4];
#pragma unroll
        for (int mt = 0; mt < 4; mt++)
#pragma unroll
            for (int nt = 0; nt < 4; nt++) acc[mt][nt] = (f32x4){0.f, 0.f, 0.f, 0.f};

        for (int k0 = 0; k0 < 512; k0 += 32) {
#pragma unroll
            for (int i = 0; i < 2; i++) {
                const int idx = t + i * 256;
                const int row = idx >> 2, seg = idx & 3;
                uint4 va = *(const uint4*)(ENCb + (size_t)(m0 + row) * 512 + k0 + seg * 8);
                uint4 vb = *(const uint4*)(Wp + (size_t)(n0 + row) * 1024 + k0 + seg * 8);
                *(uint4*)&As[row][seg * 8] = va;
                *(uint4*)&Bs[row][seg * 8] = vb;
            }
            __syncthreads();
            bf16x8 af[4], bfr[4];
#pragma unroll
            for (int mt = 0; mt < 4; mt++)
                af[mt] = *(const bf16x8*)&As[wm * 64 + mt * 16 + cc][quad * 8];
#pragma unroll
            for (int nt = 0; nt < 4; nt++)
                bfr[nt] = *(const bf16x8*)&Bs[wn * 64 + nt * 16 + cc][quad * 8];
#pragma unroll
            for (int mt = 0; mt < 4; mt++)
#pragma unroll
                for (int nt = 0; nt < 4; nt++)
                    acc[mt][nt] = __builtin_amdgcn_mfma_f32_16x16x32_bf16(af[mt], bfr[nt], acc[mt][nt], 0, 0, 0);
            __syncthreads();
        }
#pragma unroll
        for (int mt = 0; mt < 4; mt++)
#pragma unroll
            for (int nt = 0; nt < 4; nt++) g0[mt][nt] = acc[mt][nt];

        // epilogue step 1 (c0 = 0), cache ENCb residual, write h -> hb0
#pragma unroll
        for (int mt = 0; mt < 4; mt++)
#pragma unroll
            for (int r = 0; r < 4; r++) {
                const int gm = m0 + wm * 64 + mt * 16 + quad * 4 + r;
                const float gi = acc[mt][0][r] + fb0i;
                const float gf = acc[mt][1][r] + fb0f;
                const float gg = acc[mt][2][r] + fb0g;
                const float go = acc[mt][3][r] + fb0o;
                (void)gf;   // c0 = 0: forget-gate term vanishes
                const float cn = sigm(gi) * tanhf(gg);
                creg[mt][r] = cn;
                const float ev = bf2f(ENCb[(size_t)gm * 512 + j]);
                encv[mt][r] = ev;
                hb0[(size_t)gm * 512 + j] = f2bf(ev + sigm(go) * tanhf(cn));
            }
    }
    __threadfence();
    grid.sync();

    // ================= steps 2..4: K = 512..1024, A = h_prev =================
    const u16* hin = hb0;
    u16* hout = hb1;
#pragma unroll
    for (int step = 2; step <= 4; step++) {
        f32x4 acc[4][4];
#pragma unroll
        for (int mt = 0; mt < 4; mt++)
#pragma unroll
            for (int nt = 0; nt < 4; nt++) acc[mt][nt] = g0[mt][nt];

        for (int k0 = 512; k0 < 1024; k0 += 32) {
            const int kk = k0 - 512;
#pragma unroll
            for (int i = 0; i < 2; i++) {
                const int idx = t + i * 256;
                const int row = idx >> 2, seg = idx & 3;
                uint4 va = *(const uint4*)(hin + (size_t)(m0 + row) * 512 + kk + seg * 8);
                uint4 vb = *(const uint4*)(Wp + (size_t)(n0 + row) * 1024 + k0 + seg * 8);
                *(uint4*)&As[row][seg * 8] = va;
                *(uint4*)&Bs[row][seg * 8] = vb;
            }
            __syncthreads();
            bf16x8 af[4], bfr[4];
#pragma unroll
            for (int mt = 0; mt < 4; mt++)
                af[mt] = *(const bf16x8*)&As[wm * 64 + mt * 16 + cc][quad * 8];
#pragma unroll
            for (int nt = 0; nt < 4; nt++)
                bfr[nt] = *(const bf16x8*)&Bs[wn * 64 + nt * 16 + cc][quad * 8];
#pragma unroll
            for (int mt = 0; mt < 4; mt++)
#pragma unroll
                for (int nt = 0; nt < 4; nt++)
                    acc[mt][nt] = __builtin_amdgcn_mfma_f32_16x16x32_bf16(af[mt], bfr[nt], acc[mt][nt], 0, 0, 0);
            __syncthreads();
        }

#pragma unroll
        for (int mt = 0; mt < 4; mt++)
#pragma unroll
            for (int r = 0; r < 4; r++) {
                const int gm = m0 + wm * 64 + mt * 16 + quad * 4 + r;
                const float gi = acc[mt][0][r] + fb1i;
                const float gf = acc[mt][1][r] + fb1f;
                const float gg = acc[mt][2][r] + fb1g;
                const float go = acc[mt][3][r] + fb1o;
                const float cn = sigm(gf) * creg[mt][r] + sigm(gi) * tanhf(gg);
                creg[mt][r] = cn;
                const float hv = encv[mt][r] + sigm(go) * tanhf(cn);
                if (step < 4) {
                    hout[(size_t)gm * 512 + j] = f2bf(hv);
                } else {
                    // fused final dot: reduce over this quad's 16 j-lanes
                    float contrib = hv * sgj;
                    contrib += __shfl_xor(contrib, 1);
                    contrib += __shfl_xor(contrib, 2);
                    contrib += __shfl_xor(contrib, 4);
                    contrib += __shfl_xor(contrib, 8);
                    if (cc == 0) atomicAdd(&outv[gm], contrib);
                }
            }
        if (step < 4) {
            __threadfence();
            grid.sync();
            const u16* tmp = hin; hin = hout; hout = (u16*)tmp;
        }
    }
}

// ---------- classic LSTM step (FALLBACK if cooperative launch unavailable) ----------
__global__ __launch_bounds__(256)
void lstm_mfma(const u16* __restrict__ ENCb, const u16* __restrict__ hin,
               const u16* __restrict__ Wp, const float* __restrict__ fb,
               float* __restrict__ cst, u16* __restrict__ houtb,
               const float* __restrict__ sgv, float* __restrict__ outv,
               int step1, int kstart, int kend, int last)
{
    __shared__ u16 As[128][40];
    __shared__ u16 Bs[128][40];

    const int t = threadIdx.x;
    const int m0 = blockIdx.y * 128, n0 = blockIdx.x * 128;
    const int w = t >> 6, lane = t & 63, quad = lane >> 4, cc = lane & 15;
    const int wm = w >> 1, wn = w & 1;

    f32x4 acc[4][4];
#pragma unroll
    for (int mt = 0; mt < 4; mt++)
#pragma unroll
        for (int nt = 0; nt < 4; nt++) acc[mt][nt] = (f32x4){0.f, 0.f, 0.f, 0.f};

    for (int k0 = kstart; k0 < kend; k0 += 32) {
        const u16* Aptr = (k0 < 512) ? ENCb : hin;
        const int kk = (k0 < 512) ? k0 : (k0 - 512);
#pragma unroll
        for (int i = 0; i < 2; i++) {
            const int idx = t + i * 256;
            const int row = idx >> 2, seg = idx & 3;
            uint4 va = *(const uint4*)(Aptr + (size_t)(m0 + row) * 512 + kk + seg * 8);
            uint4 vb = *(const uint4*)(Wp + (size_t)(n0 + row) * 1024 + k0 + seg * 8);
            *(uint4*)&As[row][seg * 8] = va;
            *(uint4*)&Bs[row][seg * 8] = vb;
        }
        __syncthreads();

        bf16x8 af[4], bfr[4];
#pragma unroll
        for (int mt = 0; mt < 4; mt++)
            af[mt] = *(const bf16x8*)&As[wm * 64 + mt * 16 + cc][quad * 8];
#pragma unroll
        for (int nt = 0; nt < 4; nt++)
            bfr[nt] = *(const bf16x8*)&Bs[wn * 64 + nt * 16 + cc][quad * 8];
#pragma unroll
        for (int mt = 0; mt < 4; mt++)
#pragma unroll
            for (int nt = 0; nt < 4; nt++)
                acc[mt][nt] = __builtin_amdgcn_mfma_f32_16x16x32_bf16(af[mt], bfr[nt], acc[mt][nt], 0, 0, 0);
        __syncthreads();
    }

    const int j = blockIdx.x * 32 + wn * 16 + cc;
    const float fbi = fb[n0 + wn * 64 +  0 + cc];
    const float fbf = fb[n0 + wn * 64 + 16 + cc];
    const float fbg = fb[n0 + wn * 64 + 32 + cc];
    const float fbo = fb[n0 + wn * 64 + 48 + cc];
    const float sgj = last ? sgv[j] : 0.f;

#pragma unroll
    for (int mt = 0; mt < 4; mt++)
#pragma unroll
        for (int r = 0; r < 4; r++) {
            const int gm = m0 + wm * 64 + mt * 16 + quad * 4 + r;
            float gi = acc[mt][0][r] + fbi, gf = acc[mt][1][r] + fbf;
            float gg = acc[mt][2][r] + fbg, go = acc[mt][3][r] + fbo;
            const float c0 = step1 ? 0.f : cst[(size_t)gm * 512 + j];
            const float cn = sigm(gf) * c0 + sigm(gi) * tanhf(gg);
            const float hv = bf2f(ENCb[(size_t)gm * 512 + j]) + sigm(go) * tanhf(cn);
            if (last) {
                float contrib = hv * sgj;
                contrib += __shfl_xor(contrib, 1);
                contrib += __shfl_xor(contrib, 2);
                contrib += __shfl_xor(contrib, 4);
                contrib += __shfl_xor(contrib, 8);
                if (cc == 0) atomicAdd(&outv[gm], contrib);
            } else {
                cst[(size_t)gm * 512 + j] = cn;
                houtb[(size_t)gm * 512 + j] = f2bf(hv);
            }
        }
}

// ---------- row LayerNorm (wave-shuffle stats: 2 barriers) ----------
__global__ __launch_bounds__(256)
void ln_kernel(u16* __restrict__ X, const float* __restrict__ g, const float* __restrict__ b,
               float* __restrict__ supf)
{
    const int r = blockIdx.x, t = threadIdx.x;
    const int w = t >> 6, lane = t & 63;
    u16* row = X + (size_t)r * 512;
    const float x0 = bf2f(row[t]), x1 = bf2f(row[t + 256]);

    __shared__ float sr[8];
    float s = x0 + x1;
#pragma unroll
    for (int off = 32; off > 0; off >>= 1) s += __shfl_xor(s, off);
    if (lane == 0) sr[w] = s;
    __syncthreads();
    const float mu = (sr[0] + sr[1] + sr[2] + sr[3]) / 512.f;
    const float d0 = x0 - mu, d1 = x1 - mu;
    float s2 = d0 * d0 + d1 * d1;
#pragma unroll
    for (int off = 32; off > 0; off >>= 1) s2 += __shfl_xor(s2, off);
    if (lane == 0) sr[4 + w] = s2;
    __syncthreads();
    const float inv = 1.0f / sqrtf((sr[4] + sr[5] + sr[6] + sr[7]) / 512.f + 1e-5f);
    const float y0 = g[t] * d0 * inv + b[t];
    const float y1 = g[t + 256] * d1 * inv + b[t + 256];
    row[t]       = f2bf(y0);
    row[t + 256] = f2bf(y1);
    if (r >= 4096) {
        supf[(size_t)(r - 4096) * 512 + t]       = y0;
        supf[(size_t)(r - 4096) * 512 + t + 256] = y1;
    }
}

// ---------- Wp build (gate-to-nt permutation, live units only: n<2048) ----------
__global__ __launch_bounds__(256)
void wp_build(const float* __restrict__ wih, const float* __restrict__ whh,
              const float* __restrict__ bih, const float* __restrict__ bhh,
              u16* __restrict__ Wp, float* __restrict__ fb0p)
{
    const int n = blockIdx.x, t = threadIdx.x;
    const int j = (n >> 7) * 32 + ((n >> 6) & 1) * 16 + (n & 15);   // 0..511
    const int gate = (n >> 4) & 3;
    const int r = gate * 1024 + j;
    const int k = t * 4;
    float4 v;
    if (k < 512) v = *(const float4*)(wih + (size_t)r * 512 + k);
    else         v = *(const float4*)(whh + (size_t)r * 1024 + (k - 512));
    u16 o[4] = { f2bf(v.x), f2bf(v.y), f2bf(v.z), f2bf(v.w) };
    *(uint2*)(Wp + (size_t)n * 1024 + k) = *(uint2*)o;
    if (t == 0) fb0p[n] = bih[r] + bhh[r];
}

// ---------- support_g + fb1p (perm order, live units only) ----------
__global__ __launch_bounds__(256)
void sg_cvec(const float* __restrict__ supf, const float* __restrict__ whh,
             const float* __restrict__ fb0p, float* __restrict__ sg, float* __restrict__ fb1p)
{
    __shared__ float ssg[512];
    const int t = threadIdx.x;
#pragma unroll
    for (int rep = 0; rep < 2; rep++) {
        const int jj = t + rep * 256;
        float v = 0.f;
#pragma unroll
        for (int i = 0; i < 5; i++) v += supf[(size_t)i * 512 + jj];
        v *= 0.2f;
        ssg[jj] = v;
        if (blockIdx.x == 0) sg[jj] = v;
    }
    __syncthreads();
    const int n = blockIdx.x * 256 + t;          // 0..2047
    const int r = ((n >> 4) & 3) * 1024 + (n >> 7) * 32 + ((n >> 6) & 1) * 16 + (n & 15);
    float a = 0.f;
    for (int jx = 0; jx < 512; jx++)
        a = fmaf(ssg[jx], whh[(size_t)r * 1024 + 512 + jx], a);
    fb1p[n] = fb0p[n] + a;
}

// ---------- launcher ----------
extern "C" void kernel_launch(void* const* d_in, const int* in_sizes, int n_in,
                              void* d_out, int out_size, void* d_ws, size_t ws_size,
                              hipStream_t stream)
{
    (void)in_sizes; (void)n_in; (void)out_size;
    const int* query     = (const int*)d_in[0];
    const int* support   = (const int*)d_in[1];
    const int* q_l1      = (const int*)d_in[2];
    const int* q_r1      = (const int*)d_in[3];
    const int* s_l1      = (const int*)d_in[4];
    const int* s_r1      = (const int*)d_in[5];
    const float* emb     = (const float*)d_in[6];
    const float* projw   = (const float*)d_in[7];
    const float* projlb  = (const float*)d_in[8];
    const float* projb   = (const float*)d_in[9];
    const float* gatew   = (const float*)d_in[10];
    const float* gatelb  = (const float*)d_in[11];
    const float* gateb   = (const float*)d_in[12];
    const float* sew1    = (const float*)d_in[13];
    const float* seb1    = (const float*)d_in[14];
    const float* sew2    = (const float*)d_in[15];
    const float* seb2    = (const float*)d_in[16];
    const float* lng     = (const float*)d_in[17];
    const float* lnb     = (const float*)d_in[18];
    const float* wih     = (const float*)d_in[19];
    const float* whh     = (const float*)d_in[20];
    const float* bih     = (const float*)d_in[21];
    const float* bhh     = (const float*)d_in[22];

    // ---- workspace layout (float offsets) ----
    float* base   = (float*)d_ws;
    float* sg     = base;                        // 512
    float* fb0p   = base + 512;                  // 2048 used (4096 reserved)
    float* fb1p   = base + 4608;                 // 2048 used
    float* supf   = base + 8704;                 // 5*512
    u16*   projwb = (u16*)(base + 11264);        // 256*256 bf16
    u16*   sew1b  = (u16*)(base + 44032);        // 1024*512 bf16
    u16*   sew2b  = (u16*)(base + 306176);       // 512*1024 bf16
    u16*   Wp     = (u16*)(base + 568320);       // 2048*1024 bf16 (perm, live units)
    u16*   X      = (u16*)(base + 2665472);      // [4104,512]  bf16
    u16*   ENCb   = (u16*)(base + 3716096);      // [4104,512]  bf16
    u16*   hb0    = (u16*)(base + 4766720);      // [4096,512]  bf16
    u16*   hb1    = (u16*)(base + 5815296);      // [4096,512]  bf16
    float* cst    = base + 8961024;              // [4096,512]  f32 (fallback only)
    u16*   Hb     = (u16*)(base + 8961024);      // [4104,1024] bf16 (dead after GEMM2)
    u16*   embb   = (u16*)(base + 13155328);     // [100001,256] bf16 = 51.2 MB

    const size_t NEEDED      = 13155328ull * 4ull;                    //  52.6 MB
    const size_t NEEDED_EMBB = (13155328ull + 12800128ull) * 4ull;    // 103.8 MB
    if (ws_size < NEEDED) {
        signal_fail<<<16, 256, 0, stream>>>((float*)d_out);
        return;
    }
    const bool use_embb = (ws_size >= NEEDED_EMBB);

    // weight conversions (run every iteration — harness re-poisons workspace)
    hipMemsetAsync(d_out, 0, 4096 * sizeof(float), stream);
    if (use_embb)
        conv_bf16<<<2048, 256, 0, stream>>>(emb, embb, 25600256);   // 100001*256
    conv3_bf16<<<1088, 256, 0, stream>>>(projw, projwb, sew1, sew1b, sew2, sew2b);
    wp_build<<<2048, 256, 0, stream>>>(wih, whh, bih, bhh, Wp, fb0p);

    // Part A: neighbor encoders -> X (bf16); query+support merged, one side/block
    if (use_embb)
        neighbor_mfma<true><<<8202, 256, 0, stream>>>(
            q_l1, q_r1, s_l1, s_r1, query, support, emb, embb, projwb,
            projlb, projb, gatew, gatelb, gateb, X);
    else
        neighbor_mfma<false><<<8202, 256, 0, stream>>>(
            q_l1, q_r1, s_l1, s_r1, query, support, emb, nullptr, projwb,
            projlb, projb, gatew, gatelb, gateb, X);

    // Part B: support encoder (MFMA)
    gemm_bf16<<<dim3(8, 33), 256, 0, stream>>>(
        X, 512, sew1b, 512, Hb, 1024, 4101, 1024, 512, seb1, nullptr, 0, 1);
    gemm_bf16<<<dim3(4, 33), 256, 0, stream>>>(
        Hb, 1024, sew2b, 1024, ENCb, 512, 4101, 512, 1024, seb2, X, 512, 0);
    ln_kernel<<<4101, 256, 0, stream>>>(ENCb, lng, lnb, supf);

    sg_cvec<<<8, 256, 0, stream>>>(supf, whh, fb0p, sg, fb1p);

    // LSTM: fused cooperative kernel (g0 + c + ENCb residual in registers,
    // grid.sync between steps); fallback = classic 4-launch path.
    float* outv = (float*)d_out;
    {
        void* args[] = { (void*)&ENCb, (void*)&hb0, (void*)&hb1, (void*)&Wp,
                         (void*)&fb0p, (void*)&fb1p, (void*)&sg, (void*)&outv };
        hipError_t err = hipLaunchCooperativeKernel(
            (const void*)lstm_fused, dim3(16, 32), dim3(256), args, 0, stream);
        if (err != hipSuccess) {
            (void)hipGetLastError();   // clear
            lstm_mfma<<<dim3(16, 32), 256, 0, stream>>>(ENCb, hb0, Wp, fb0p, cst, hb0, sg, outv, 1, 0, 512, 0);
            lstm_mfma<<<dim3(16, 32), 256, 0, stream>>>(ENCb, hb0, Wp, fb1p, cst, hb1, sg, outv, 0, 0, 1024, 0);
            lstm_mfma<<<dim3(16, 32), 256, 0, stream>>>(ENCb, hb1, Wp, fb1p, cst, hb0, sg, outv, 0, 0, 1024, 0);
            lstm_mfma<<<dim3(16, 32), 256, 0, stream>>>(ENCb, hb0, Wp, fb1p, cst, hb1, sg, outv, 0, 0, 1024, 1);
        }
    }
}

// Round 11
// 630.702 us; speedup vs baseline: 1.4887x; 1.4887x over previous
//
#include <hip/hip_runtime.h>
#include <hip/hip_bf16.h>

typedef unsigned short u16;
typedef unsigned int   u32;
typedef __attribute__((ext_vector_type(8))) short bf16x8;   // 8 bf16 = 4 VGPRs
typedef __attribute__((ext_vector_type(4))) float f32x4;

// ---------- helpers ----------
__device__ __forceinline__ float bf2f(u16 u) {
    union { u32 i; float f; } v; v.i = ((u32)u) << 16; return v.f;
}
__device__ __forceinline__ u16 f2bf(float f) {
    __hip_bfloat16 h = __float2bfloat16(f);
    return *reinterpret_cast<u16*>(&h);
}
__device__ __forceinline__ float sigm(float x) { return 1.0f / (1.0f + expf(-x)); }

#define PAD_IDX 100000

// ---------- workspace-too-small sentinel ----------
__global__ __launch_bounds__(256)
void signal_fail(float* out) {
    int i = blockIdx.x * 256 + threadIdx.x;
    if (i < 4096) out[i] = 12345.0f;
}

// ---------- f32 -> bf16 conversion ----------
// (R9: harness re-poisons the workspace between iterations — weight prep cannot
//  be cached, runs every iteration. R10: holding LSTM state in registers spills
//  at VGPR=128 — persistent state must live in L2-backed buffers (A1), not VGPRs.)
__global__ __launch_bounds__(256)
void conv_bf16(const float* __restrict__ in, u16* __restrict__ out, long n) {
    long i = ((long)blockIdx.x * 256 + threadIdx.x) * 4;
    const long stride = (long)gridDim.x * 256 * 4;
    for (; i < n; i += stride) {
        float4 v = *(const float4*)(in + i);
        u16 o[4] = { f2bf(v.x), f2bf(v.y), f2bf(v.z), f2bf(v.w) };
        *(uint2*)(out + i) = *(uint2*)o;
    }
}

// ---------- fused small-weight conversions (projw | sew1 | sew2) ----------
__global__ __launch_bounds__(256)
void conv3_bf16(const float* __restrict__ projw, u16* __restrict__ projwb,
                const float* __restrict__ sew1, u16* __restrict__ sew1b,
                const float* __restrict__ sew2, u16* __restrict__ sew2b)
{
    const float* in; u16* out; long n, b0;
    const int bx = blockIdx.x;
    if (bx < 64)        { in = projw; out = projwb; n = 65536;  b0 = bx; }
    else if (bx < 576)  { in = sew1;  out = sew1b;  n = 524288; b0 = bx - 64; }
    else                { in = sew2;  out = sew2b;  n = 524288; b0 = bx - 576; }
    long i = (b0 * 256 + threadIdx.x) * 4;
    if (i < n) {
        float4 v = *(const float4*)(in + i);
        u16 o[4] = { f2bf(v.x), f2bf(v.y), f2bf(v.z), f2bf(v.w) };
        *(uint2*)(out + i) = *(uint2*)o;
    }
}

// ---------- Part A: neighbor encoder (R6-exact: one side per block) ----------
// Merged grid: blocks [0,8192) = query (side = bid>>12, b = bid&4095),
// blocks [8192,8202) = support. BF16E: full-batch 26-load gather per wave.
// Measured best: 205us. The gather pattern (random 512B rows of a 51MB table)
// plateaus at ~4 TB/s demand regardless of occupancy; R7's forced-occupancy
// attempt spilled (VGPR 32, 965MB scratch) and regressed 2.4x. Do NOT add
// __launch_bounds__ min-wave hints: natural VGPR is ~88.
template<bool BF16E>
__global__ __launch_bounds__(256)
void neighbor_mfma(const int* __restrict__ q_l1, const int* __restrict__ q_r1,
                   const int* __restrict__ s_l1, const int* __restrict__ s_r1,
                   const int* __restrict__ query, const int* __restrict__ support,
                   const float* __restrict__ emb, const u16* __restrict__ embb,
                   const u16* __restrict__ projw_b,
                   const float* __restrict__ projlb, const float* __restrict__ projb,
                   const float* __restrict__ gatew, const float* __restrict__ gatelb,
                   const float* __restrict__ gateb,
                   u16* __restrict__ outX)
{
    __shared__ u16   nvA[64][264];     // [k-row][d], pad 256->264
    __shared__ __align__(8) int sconn[100];
    __shared__ float maskv[64];
    __shared__ float sagg[256];
    __shared__ float sred4[4];
    __shared__ float scnt;

    const int bid = blockIdx.x;
    const int* __restrict__ conn;
    const int* __restrict__ sel;
    int b, side, row_off;
    if (bid < 8192) {
        side = bid >> 12; b = bid & 4095;
        conn = side ? q_r1 : q_l1; sel = query; row_off = 0;
    } else {
        const int i = bid - 8192;
        side = i / 5; b = i - side * 5;
        conn = side ? s_r1 : s_l1; sel = support; row_off = 4096;
    }
    const int col_off = side * 256;

    const int t = threadIdx.x;
    const int w = t >> 6, lane = t & 63, quad = lane >> 4, cc = lane & 15;

    if (t < 100) sconn[t] = conn[b * 100 + t];
    const int sid = sel[b * 2 + side];
    const float selfv = emb[(size_t)sid * 256 + t];   // f32 self row (accuracy)
    __syncthreads();

    if (BF16E) {
        // ---- full-batch prefetch: wave w owns k = w + 4*kk ----
        const int nslots = (w < 2) ? 13 : 12;          // wave-uniform
        uint2 ra[13], re[13];
#pragma unroll
        for (int kk = 0; kk < 13; kk++) {
            if (kk < nslots) {
                const int k = w + kk * 4;
                const int2 id = *(const int2*)&sconn[2 * k];
                ra[kk] = *(const uint2*)(embb + (size_t)id.x * 256 + lane * 4);
                re[kk] = *(const uint2*)(embb + (size_t)id.y * 256 + lane * 4);
            }
        }
        // independent work hides under the in-flight loads
        float cnt = 0.f;
        for (int k = 0; k < 50; k++) if (sconn[2 * k] != PAD_IDX) cnt += 1.f;
        if (t < 64) maskv[t] = (t < 50 && sconn[2 * t] != PAD_IDX) ? 1.f : 0.f;
        for (int k = 50; k < 64; k++) nvA[k][t] = 0;
        if (t == 0) scnt = cnt;

#pragma unroll
        for (int kk = 0; kk < 13; kk++) {
            if (kk < nslots) {
                const int k = w + kk * 4;
                u16 o[4];
                o[0] = f2bf(bf2f((u16)(ra[kk].x & 0xffff)) * bf2f((u16)(re[kk].x & 0xffff)));
                o[1] = f2bf(bf2f((u16)(ra[kk].x >> 16))    * bf2f((u16)(re[kk].x >> 16)));
                o[2] = f2bf(bf2f((u16)(ra[kk].y & 0xffff)) * bf2f((u16)(re[kk].y & 0xffff)));
                o[3] = f2bf(bf2f((u16)(ra[kk].y >> 16))    * bf2f((u16)(re[kk].y >> 16)));
                *(uint2*)&nvA[k][lane * 4] = *(uint2*)o;
            }
        }
    } else {
        // f32 fallback: float4 rows, 1-deep prefetch
        float cnt = 0.f;
        for (int k = 0; k < 50; k++) if (sconn[2 * k] != PAD_IDX) cnt += 1.f;
        if (t < 64) maskv[t] = (t < 50 && sconn[2 * t] != PAD_IDX) ? 1.f : 0.f;
        for (int k = 50; k < 64; k++) nvA[k][t] = 0;
        if (t == 0) scnt = cnt;

        int k = w;
        float4 rra, rre;
        {
            const int rel = sconn[2 * k], ent = sconn[2 * k + 1];
            rra = *(const float4*)(emb + (size_t)rel * 256 + lane * 4);
            rre = *(const float4*)(emb + (size_t)ent * 256 + lane * 4);
        }
        while (true) {
            const int kn = k + 4;
            float4 na, ne;
            if (kn < 50) {
                const int rel = sconn[2 * kn], ent = sconn[2 * kn + 1];
                na = *(const float4*)(emb + (size_t)rel * 256 + lane * 4);
                ne = *(const float4*)(emb + (size_t)ent * 256 + lane * 4);
            }
            u16 o[4] = { f2bf(rra.x * rre.x), f2bf(rra.y * rre.y),
                         f2bf(rra.z * rre.z), f2bf(rra.w * rre.w) };
            *(uint2*)&nvA[k][lane * 4] = *(uint2*)o;
            if (kn >= 50) break;
            rra = na; rre = ne; k = kn;
        }
    }
    __syncthreads();
    const float cnt = scnt;

    f32x4 acc[4][4];
#pragma unroll
    for (int mt = 0; mt < 4; mt++)
#pragma unroll
        for (int nt = 0; nt < 4; nt++) acc[mt][nt] = (f32x4){0.f, 0.f, 0.f, 0.f};

    for (int k0 = 0; k0 < 256; k0 += 32) {
        bf16x8 a[4];
#pragma unroll
        for (int mt = 0; mt < 4; mt++)
            a[mt] = *(const bf16x8*)&nvA[mt * 16 + cc][k0 + quad * 8];
#pragma unroll
        for (int nt = 0; nt < 4; nt++) {
            const int e = (w * 4 + nt) * 16 + cc;
            bf16x8 bv = *(const bf16x8*)(projw_b + (size_t)e * 256 + k0 + quad * 8);
#pragma unroll
            for (int mt = 0; mt < 4; mt++)
                acc[mt][nt] = __builtin_amdgcn_mfma_f32_16x16x32_bf16(a[mt], bv, acc[mt][nt], 0, 0, 0);
        }
    }

    float pbv[4], cs[4] = {0.f, 0.f, 0.f, 0.f};
#pragma unroll
    for (int nt = 0; nt < 4; nt++) {
        const int e = (w * 4 + nt) * 16 + cc;
        pbv[nt] = projlb[e] + projb[e];
    }
#pragma unroll
    for (int mt = 0; mt < 4; mt++)
#pragma unroll
        for (int r = 0; r < 4; r++) {
            const float mk = maskv[mt * 16 + quad * 4 + r];
#pragma unroll
            for (int nt = 0; nt < 4; nt++) {
                float v = acc[mt][nt][r] + pbv[nt];
                v = v > 0.f ? v : 0.01f * v;     // leaky_relu(0.01)
                cs[nt] += mk * v;
            }
        }
#pragma unroll
    for (int nt = 0; nt < 4; nt++) {
        cs[nt] += __shfl_xor(cs[nt], 16);
        cs[nt] += __shfl_xor(cs[nt], 32);
    }
    if (quad == 0) {
#pragma unroll
        for (int nt = 0; nt < 4; nt++) sagg[(w * 4 + nt) * 16 + cc] = cs[nt];
    }
    __syncthreads();

    const float agg = sagg[t] / (cnt + 1e-9f);
    // gate dot: wave shuffle reduce (2 barriers total)
    float gv = selfv * gatew[t] + agg * gatew[256 + t];
#pragma unroll
    for (int off = 32; off > 0; off >>= 1) gv += __shfl_xor(gv, off);
    if (lane == 0) sred4[w] = gv;
    __syncthreads();
    const float sgate = sigm(sred4[0] + sred4[1] + sred4[2] + sred4[3]
                             + gatelb[0] + gateb[0]);
    outX[(size_t)(row_off + b) * 512 + col_off + t] = f2bf(tanhf(selfv + sgate * agg));
}

// ---------- generic bf16 MFMA GEMM: C = act(A @ B^T + bias_f32 + resid_bf16) ----------
__global__ __launch_bounds__(256)
void gemm_bf16(const u16* __restrict__ A, int lda, const u16* __restrict__ B, int ldb,
               u16* __restrict__ C, int ldc, int M, int N, int K,
               const float* __restrict__ bias, const u16* __restrict__ resid, int ldr, int act)
{
    __shared__ u16 As[128][40];
    __shared__ u16 Bs[128][40];

    const int t = threadIdx.x;
    const int m0 = blockIdx.y * 128, n0 = blockIdx.x * 128;
    const int w = t >> 6, lane = t & 63, quad = lane >> 4, cc = lane & 15;
    const int wm = w >> 1, wn = w & 1;

    f32x4 acc[4][4];
#pragma unroll
    for (int mt = 0; mt < 4; mt++)
#pragma unroll
        for (int nt = 0; nt < 4; nt++) acc[mt][nt] = (f32x4){0.f, 0.f, 0.f, 0.f};

    for (int k0 = 0; k0 < K; k0 += 32) {
#pragma unroll
        for (int i = 0; i < 2; i++) {
            const int idx = t + i * 256;
            const int row = idx >> 2, seg = idx & 3;
            const int gm = m0 + row, gn = n0 + row;
            uint4 va = make_uint4(0, 0, 0, 0), vb = make_uint4(0, 0, 0, 0);
            if (gm < M) va = *(const uint4*)(A + (size_t)gm * lda + k0 + seg * 8);
            if (gn < N) vb = *(const uint4*)(B + (size_t)gn * ldb + k0 + seg * 8);
            *(uint4*)&As[row][seg * 8] = va;
            *(uint4*)&Bs[row][seg * 8] = vb;
        }
        __syncthreads();

        bf16x8 af[4], bfr[4];
#pragma unroll
        for (int mt = 0; mt < 4; mt++)
            af[mt] = *(const bf16x8*)&As[wm * 64 + mt * 16 + cc][quad * 8];
#pragma unroll
        for (int nt = 0; nt < 4; nt++)
            bfr[nt] = *(const bf16x8*)&Bs[wn * 64 + nt * 16 + cc][quad * 8];
#pragma unroll
        for (int mt = 0; mt < 4; mt++)
#pragma unroll
            for (int nt = 0; nt < 4; nt++)
                acc[mt][nt] = __builtin_amdgcn_mfma_f32_16x16x32_bf16(af[mt], bfr[nt], acc[mt][nt], 0, 0, 0);
        __syncthreads();
    }

#pragma unroll
    for (int mt = 0; mt < 4; mt++)
#pragma unroll
        for (int r = 0; r < 4; r++) {
            const int gm = m0 + wm * 64 + mt * 16 + quad * 4 + r;
            if (gm >= M) continue;
#pragma unroll
            for (int nt = 0; nt < 4; nt++) {
                const int gn = n0 + wn * 64 + nt * 16 + cc;
                if (gn >= N) continue;
                float x = acc[mt][nt][r];
                if (bias)  x += bias[gn];
                if (resid) x += bf2f(resid[(size_t)gm * ldr + gn]);
                if (act == 1) x = x > 0.f ? x : 0.f;
                C[(size_t)gm * ldc + gn] = f2bf(x);
            }
        }
}

// ---------- LSTM step, DEAD-UNIT-HALVED (units j<512 live), fused final dot ----------
// Reference: h = query + h_new[:, :512]; r = support_g (softmax over 1 row = 1),
// so gate rows for units >=512 are dead. N = 2048, grid (16,32).
// a1mode: 0=none, 1=store A1 (raw ENC@Wih acc), 2=load A1 and add (L2-resident
// 16.8MB bf16 — the affordable form of g0 reuse; R10 showed registers spill).
// last: fuse the final score: out[gm] += sum_j hv(gm,j)*sg[j] (quad-shuffle +
// one atomicAdd per 16 lanes; d_out pre-zeroed by hipMemsetAsync).
__global__ __launch_bounds__(256)
void lstm_mfma(const u16* __restrict__ ENCb, const u16* __restrict__ hin,
               const u16* __restrict__ Wp, const float* __restrict__ fb,
               float* __restrict__ cst, u16* __restrict__ houtb,
               const float* __restrict__ sgv, float* __restrict__ outv,
               u16* __restrict__ A1, int step1, int kstart, int kend, int a1mode, int last)
{
    __shared__ u16 As[128][40];
    __shared__ u16 Bs[128][40];

    const int t = threadIdx.x;
    const int m0 = blockIdx.y * 128, n0 = blockIdx.x * 128;
    const int w = t >> 6, lane = t & 63, quad = lane >> 4, cc = lane & 15;
    const int wm = w >> 1, wn = w & 1;

    f32x4 acc[4][4];
#pragma unroll
    for (int mt = 0; mt < 4; mt++)
#pragma unroll
        for (int nt = 0; nt < 4; nt++) acc[mt][nt] = (f32x4){0.f, 0.f, 0.f, 0.f};

    for (int k0 = kstart; k0 < kend; k0 += 32) {
        const u16* Aptr = (k0 < 512) ? ENCb : hin;
        const int kk = (k0 < 512) ? k0 : (k0 - 512);
#pragma unroll
        for (int i = 0; i < 2; i++) {
            const int idx = t + i * 256;
            const int row = idx >> 2, seg = idx & 3;
            uint4 va = *(const uint4*)(Aptr + (size_t)(m0 + row) * 512 + kk + seg * 8);
            uint4 vb = *(const uint4*)(Wp + (size_t)(n0 + row) * 1024 + k0 + seg * 8);
            *(uint4*)&As[row][seg * 8] = va;
            *(uint4*)&Bs[row][seg * 8] = vb;
        }
        __syncthreads();

        bf16x8 af[4], bfr[4];
#pragma unroll
        for (int mt = 0; mt < 4; mt++)
            af[mt] = *(const bf16x8*)&As[wm * 64 + mt * 16 + cc][quad * 8];
#pragma unroll
        for (int nt = 0; nt < 4; nt++)
            bfr[nt] = *(const bf16x8*)&Bs[wn * 64 + nt * 16 + cc][quad * 8];
#pragma unroll
        for (int mt = 0; mt < 4; mt++)
#pragma unroll
            for (int nt = 0; nt < 4; nt++)
                acc[mt][nt] = __builtin_amdgcn_mfma_f32_16x16x32_bf16(af[mt], bfr[nt], acc[mt][nt], 0, 0, 0);
        __syncthreads();
    }

    // epilogue: lane owns gates (i,f,g,o) of unit j<512 for 16 rows
    const int j = blockIdx.x * 32 + wn * 16 + cc;            // 0..511
    const float fbi = fb[n0 + wn * 64 +  0 + cc];
    const float fbf = fb[n0 + wn * 64 + 16 + cc];
    const float fbg = fb[n0 + wn * 64 + 32 + cc];
    const float fbo = fb[n0 + wn * 64 + 48 + cc];
    const float sgj = last ? sgv[j] : 0.f;

#pragma unroll
    for (int mt = 0; mt < 4; mt++)
#pragma unroll
        for (int r = 0; r < 4; r++) {
            const int gm = m0 + wm * 64 + mt * 16 + quad * 4 + r;
            float gi = acc[mt][0][r], gf = acc[mt][1][r];
            float gg = acc[mt][2][r], go = acc[mt][3][r];
            const size_t a1idx = (((size_t)blockIdx.x * 4096 + gm) * 128 + wn * 64 + cc * 4);
            if (a1mode == 1) {
                u16 o[4] = { f2bf(gi), f2bf(gf), f2bf(gg), f2bf(go) };
                *(uint2*)(A1 + a1idx) = *(uint2*)o;
            } else if (a1mode == 2) {
                uint2 v = *(const uint2*)(A1 + a1idx);
                gi += bf2f((u16)(v.x & 0xffff)); gf += bf2f((u16)(v.x >> 16));
                gg += bf2f((u16)(v.y & 0xffff)); go += bf2f((u16)(v.y >> 16));
            }
            gi += fbi; gf += fbf; gg += fbg; go += fbo;
            const float c0 = step1 ? 0.f : cst[(size_t)gm * 512 + j];
            const float cn = sigm(gf) * c0 + sigm(gi) * tanhf(gg);
            const float hv = bf2f(ENCb[(size_t)gm * 512 + j]) + sigm(go) * tanhf(cn);
            if (last) {
                float contrib = hv * sgj;
                contrib += __shfl_xor(contrib, 1);
                contrib += __shfl_xor(contrib, 2);
                contrib += __shfl_xor(contrib, 4);
                contrib += __shfl_xor(contrib, 8);
                if (cc == 0) atomicAdd(&outv[gm], contrib);
            } else {
                cst[(size_t)gm * 512 + j] = cn;
                houtb[(size_t)gm * 512 + j] = f2bf(hv);
            }
        }
}

// ---------- row LayerNorm (wave-shuffle stats: 2 barriers) ----------
__global__ __launch_bounds__(256)
void ln_kernel(u16* __restrict__ X, const float* __restrict__ g, const float* __restrict__ b,
               float* __restrict__ supf)
{
    const int r = blockIdx.x, t = threadIdx.x;
    const int w = t >> 6, lane = t & 63;
    u16* row = X + (size_t)r * 512;
    const float x0 = bf2f(row[t]), x1 = bf2f(row[t + 256]);

    __shared__ float sr[8];
    float s = x0 + x1;
#pragma unroll
    for (int off = 32; off > 0; off >>= 1) s += __shfl_xor(s, off);
    if (lane == 0) sr[w] = s;
    __syncthreads();
    const float mu = (sr[0] + sr[1] + sr[2] + sr[3]) / 512.f;
    const float d0 = x0 - mu, d1 = x1 - mu;
    float s2 = d0 * d0 + d1 * d1;
#pragma unroll
    for (int off = 32; off > 0; off >>= 1) s2 += __shfl_xor(s2, off);
    if (lane == 0) sr[4 + w] = s2;
    __syncthreads();
    const float inv = 1.0f / sqrtf((sr[4] + sr[5] + sr[6] + sr[7]) / 512.f + 1e-5f);
    const float y0 = g[t] * d0 * inv + b[t];
    const float y1 = g[t + 256] * d1 * inv + b[t + 256];
    row[t]       = f2bf(y0);
    row[t + 256] = f2bf(y1);
    if (r >= 4096) {
        supf[(size_t)(r - 4096) * 512 + t]       = y0;
        supf[(size_t)(r - 4096) * 512 + t + 256] = y1;
    }
}

// ---------- Wp build (gate-to-nt permutation, live units only: n<2048) ----------
__global__ __launch_bounds__(256)
void wp_build(const float* __restrict__ wih, const float* __restrict__ whh,
              const float* __restrict__ bih, const float* __restrict__ bhh,
              u16* __restrict__ Wp, float* __restrict__ fb0p)
{
    const int n = blockIdx.x, t = threadIdx.x;
    const int j = (n >> 7) * 32 + ((n >> 6) & 1) * 16 + (n & 15);   // 0..511
    const int gate = (n >> 4) & 3;
    const int r = gate * 1024 + j;
    const int k = t * 4;
    float4 v;
    if (k < 512) v = *(const float4*)(wih + (size_t)r * 512 + k);
    else         v = *(const float4*)(whh + (size_t)r * 1024 + (k - 512));
    u16 o[4] = { f2bf(v.x), f2bf(v.y), f2bf(v.z), f2bf(v.w) };
    *(uint2*)(Wp + (size_t)n * 1024 + k) = *(uint2*)o;
    if (t == 0) fb0p[n] = bih[r] + bhh[r];
}

// ---------- support_g + fb1p (perm order, live units only) ----------
__global__ __launch_bounds__(256)
void sg_cvec(const float* __restrict__ supf, const float* __restrict__ whh,
             const float* __restrict__ fb0p, float* __restrict__ sg, float* __restrict__ fb1p)
{
    __shared__ float ssg[512];
    const int t = threadIdx.x;
#pragma unroll
    for (int rep = 0; rep < 2; rep++) {
        const int jj = t + rep * 256;
        float v = 0.f;
#pragma unroll
        for (int i = 0; i < 5; i++) v += supf[(size_t)i * 512 + jj];
        v *= 0.2f;
        ssg[jj] = v;
        if (blockIdx.x == 0) sg[jj] = v;
    }
    __syncthreads();
    const int n = blockIdx.x * 256 + t;          // 0..2047
    const int r = ((n >> 4) & 3) * 1024 + (n >> 7) * 32 + ((n >> 6) & 1) * 16 + (n & 15);
    float a = 0.f;
    for (int jx = 0; jx < 512; jx++)
        a = fmaf(ssg[jx], whh[(size_t)r * 1024 + 512 + jx], a);
    fb1p[n] = fb0p[n] + a;
}

// ---------- launcher ----------
extern "C" void kernel_launch(void* const* d_in, const int* in_sizes, int n_in,
                              void* d_out, int out_size, void* d_ws, size_t ws_size,
                              hipStream_t stream)
{
    (void)in_sizes; (void)n_in; (void)out_size;
    const int* query     = (const int*)d_in[0];
    const int* support   = (const int*)d_in[1];
    const int* q_l1      = (const int*)d_in[2];
    const int* q_r1      = (const int*)d_in[3];
    const int* s_l1      = (const int*)d_in[4];
    const int* s_r1      = (const int*)d_in[5];
    const float* emb     = (const float*)d_in[6];
    const float* projw   = (const float*)d_in[7];
    const float* projlb  = (const float*)d_in[8];
    const float* projb   = (const float*)d_in[9];
    const float* gatew   = (const float*)d_in[10];
    const float* gatelb  = (const float*)d_in[11];
    const float* gateb   = (const float*)d_in[12];
    const float* sew1    = (const float*)d_in[13];
    const float* seb1    = (const float*)d_in[14];
    const float* sew2    = (const float*)d_in[15];
    const float* seb2    = (const float*)d_in[16];
    const float* lng     = (const float*)d_in[17];
    const float* lnb     = (const float*)d_in[18];
    const float* wih     = (const float*)d_in[19];
    const float* whh     = (const float*)d_in[20];
    const float* bih     = (const float*)d_in[21];
    const float* bhh     = (const float*)d_in[22];

    // ---- workspace layout (float offsets) ----
    float* base   = (float*)d_ws;
    float* sg     = base;                        // 512
    float* fb0p   = base + 512;                  // 2048 used (4096 reserved)
    float* fb1p   = base + 4608;                 // 2048 used
    float* supf   = base + 8704;                 // 5*512
    u16*   projwb = (u16*)(base + 11264);        // 256*256 bf16
    u16*   sew1b  = (u16*)(base + 44032);        // 1024*512 bf16
    u16*   sew2b  = (u16*)(base + 306176);       // 512*1024 bf16
    u16*   Wp     = (u16*)(base + 568320);       // 2048*1024 bf16 (perm, live units)
    u16*   X      = (u16*)(base + 2665472);      // [4104,512]  bf16
    u16*   ENCb   = (u16*)(base + 3716096);      // [4104,512]  bf16
    u16*   hb0    = (u16*)(base + 4766720);      // [4096,512]  bf16
    u16*   hb1    = (u16*)(base + 5815296);      // [4096,512]  bf16
    float* cst    = base + 8961024;              // [4096,512]  f32 (overlays Hb region)
    u16*   Hb     = (u16*)(base + 8961024);      // [4104,1024] bf16 (dead after GEMM2)
    // tiered region: embb (bf16 emb table, 12800128 floats) and/or A1 (4194304 floats)
    u16*   embb   = (u16*)(base + 13155328);     // [100001,256] bf16 = 51.2 MB
    u16*   A1_hi  = (u16*)(base + 25955456);     // behind embb: 16*4096*128 bf16 = 16.8 MB
    u16*   A1_lo  = (u16*)(base + 13155328);     // legacy position (no embb)

    const size_t NEEDED      = 13155328ull * 4ull;                    //  52.6 MB
    const size_t NEEDED_A1   = (13155328ull +  4194304ull) * 4ull;    //  69.4 MB
    const size_t NEEDED_EMBB = (13155328ull + 12800128ull) * 4ull;    // 103.8 MB
    const size_t NEEDED_ALL  = (25955456ull +  4194304ull) * 4ull;    // 120.6 MB
    if (ws_size < NEEDED) {
        signal_fail<<<16, 256, 0, stream>>>((float*)d_out);
        return;
    }
    const bool use_embb = (ws_size >= NEEDED_EMBB);
    u16* A1 = nullptr;
    bool use_a1 = false;
    if (ws_size >= NEEDED_ALL)                    { use_a1 = true; A1 = A1_hi; }
    else if (!use_embb && ws_size >= NEEDED_A1)   { use_a1 = true; A1 = A1_lo; }

    // weight conversions (run every iteration — harness re-poisons workspace)
    hipMemsetAsync(d_out, 0, 4096 * sizeof(float), stream);
    if (use_embb)
        conv_bf16<<<2048, 256, 0, stream>>>(emb, embb, 25600256);   // 100001*256
    conv3_bf16<<<1088, 256, 0, stream>>>(projw, projwb, sew1, sew1b, sew2, sew2b);
    wp_build<<<2048, 256, 0, stream>>>(wih, whh, bih, bhh, Wp, fb0p);

    // Part A: neighbor encoders -> X (bf16); query+support merged, one side/block
    if (use_embb)
        neighbor_mfma<true><<<8202, 256, 0, stream>>>(
            q_l1, q_r1, s_l1, s_r1, query, support, emb, embb, projwb,
            projlb, projb, gatew, gatelb, gateb, X);
    else
        neighbor_mfma<false><<<8202, 256, 0, stream>>>(
            q_l1, q_r1, s_l1, s_r1, query, support, emb, nullptr, projwb,
            projlb, projb, gatew, gatelb, gateb, X);

    // Part B: support encoder (MFMA)
    gemm_bf16<<<dim3(8, 33), 256, 0, stream>>>(
        X, 512, sew1b, 512, Hb, 1024, 4101, 1024, 512, seb1, nullptr, 0, 1);
    gemm_bf16<<<dim3(4, 33), 256, 0, stream>>>(
        Hb, 1024, sew2b, 1024, ENCb, 512, 4101, 512, 1024, seb2, X, 512, 0);
    ln_kernel<<<4101, 256, 0, stream>>>(ENCb, lng, lnb, supf);

    sg_cvec<<<8, 256, 0, stream>>>(supf, whh, fb0p, sg, fb1p);

    // LSTM: N=2048 (dead units >=512 eliminated); step 4 fuses the final dot
    float* outv = (float*)d_out;
    if (use_a1) {
        lstm_mfma<<<dim3(16, 32), 256, 0, stream>>>(ENCb, hb0, Wp, fb0p, cst, hb0, sg, outv, A1, 1, 0, 512, 1, 0);
        lstm_mfma<<<dim3(16, 32), 256, 0, stream>>>(ENCb, hb0, Wp, fb1p, cst, hb1, sg, outv, A1, 0, 512, 1024, 2, 0);
        lstm_mfma<<<dim3(16, 32), 256, 0, stream>>>(ENCb, hb1, Wp, fb1p, cst, hb0, sg, outv, A1, 0, 512, 1024, 2, 0);
        lstm_mfma<<<dim3(16, 32), 256, 0, stream>>>(ENCb, hb0, Wp, fb1p, cst, hb1, sg, outv, A1, 0, 512, 1024, 2, 1);
    } else {
        lstm_mfma<<<dim3(16, 32), 256, 0, stream>>>(ENCb, hb0, Wp, fb0p, cst, hb0, sg, outv, nullptr, 1, 0, 512, 0, 0);
        lstm_mfma<<<dim3(16, 32), 256, 0, stream>>>(ENCb, hb0, Wp, fb1p, cst, hb1, sg, outv, nullptr, 0, 0, 1024, 0, 0);
        lstm_mfma<<<dim3(16, 32), 256, 0, stream>>>(ENCb, hb1, Wp, fb1p, cst, hb0, sg, outv, nullptr, 0, 0, 1024, 0, 0);
        lstm_mfma<<<dim3(16, 32), 256, 0, stream>>>(ENCb, hb0, Wp, fb1p, cst, hb1, sg, outv, nullptr, 0, 0, 1024, 0, 1);
    }
}

// Round 12
// 615.078 us; speedup vs baseline: 1.5265x; 1.0254x over previous
//
#include <hip/hip_runtime.h>
#include <hip/hip_bf16.h>

typedef unsigned short u16;
typedef unsigned int   u32;
typedef __attribute__((ext_vector_type(8))) short bf16x8;   // 8 bf16 = 4 VGPRs
typedef __attribute__((ext_vector_type(4))) float f32x4;

// ---------- helpers ----------
__device__ __forceinline__ float bf2f(u16 u) {
    union { u32 i; float f; } v; v.i = ((u32)u) << 16; return v.f;
}
__device__ __forceinline__ u16 f2bf(float f) {
    __hip_bfloat16 h = __float2bfloat16(f);
    return *reinterpret_cast<u16*>(&h);
}
__device__ __forceinline__ float sigm(float x) { return 1.0f / (1.0f + expf(-x)); }

// async global->LDS DMA, 16B per lane: LDS dest = wave-uniform base + lane*16,
// global source per-lane. Completion tracked by vmcnt (drained at __syncthreads).
__device__ __forceinline__ void gload16(const u16* g, u16* l) {
    __builtin_amdgcn_global_load_lds(
        (const __attribute__((address_space(1))) u32*)(const void*)g,
        (__attribute__((address_space(3))) u32*)(void*)l, 16, 0, 0);
}

#define PAD_IDX 100000

// ---------- workspace-too-small sentinel ----------
__global__ __launch_bounds__(256)
void signal_fail(float* out) {
    int i = blockIdx.x * 256 + threadIdx.x;
    if (i < 4096) out[i] = 12345.0f;
}

// ---------- f32 -> bf16 conversion ----------
// (R9: harness re-poisons workspace between iterations — weight prep cannot be
//  cached. R10: persistent LSTM state in registers spills — use L2 buffers.)
__global__ __launch_bounds__(256)
void conv_bf16(const float* __restrict__ in, u16* __restrict__ out, long n) {
    long i = ((long)blockIdx.x * 256 + threadIdx.x) * 4;
    const long stride = (long)gridDim.x * 256 * 4;
    for (; i < n; i += stride) {
        float4 v = *(const float4*)(in + i);
        u16 o[4] = { f2bf(v.x), f2bf(v.y), f2bf(v.z), f2bf(v.w) };
        *(uint2*)(out + i) = *(uint2*)o;
    }
}

// ---------- fused small-weight conversions (projw | sew1 | sew2) ----------
__global__ __launch_bounds__(256)
void conv3_bf16(const float* __restrict__ projw, u16* __restrict__ projwb,
                const float* __restrict__ sew1, u16* __restrict__ sew1b,
                const float* __restrict__ sew2, u16* __restrict__ sew2b)
{
    const float* in; u16* out; long n, b0;
    const int bx = blockIdx.x;
    if (bx < 64)        { in = projw; out = projwb; n = 65536;  b0 = bx; }
    else if (bx < 576)  { in = sew1;  out = sew1b;  n = 524288; b0 = bx - 64; }
    else                { in = sew2;  out = sew2b;  n = 524288; b0 = bx - 576; }
    long i = (b0 * 256 + threadIdx.x) * 4;
    if (i < n) {
        float4 v = *(const float4*)(in + i);
        u16 o[4] = { f2bf(v.x), f2bf(v.y), f2bf(v.z), f2bf(v.w) };
        *(uint2*)(out + i) = *(uint2*)o;
    }
}

// ---------- Part A: neighbor encoder (R6-exact, measured plateau 205us) ----------
// Merged grid: blocks [0,8192) = query, [8192,8202) = support. Full-batch
// 26-load gather/wave. Random 512B-row gather of 51MB table plateaus ~4 TB/s
// demand regardless of occupancy (R2/R3/R6); forced-occupancy spills (R7).
// Do NOT add __launch_bounds__ min-wave hints: natural VGPR ~88.
template<bool BF16E>
__global__ __launch_bounds__(256)
void neighbor_mfma(const int* __restrict__ q_l1, const int* __restrict__ q_r1,
                   const int* __restrict__ s_l1, const int* __restrict__ s_r1,
                   const int* __restrict__ query, const int* __restrict__ support,
                   const float* __restrict__ emb, const u16* __restrict__ embb,
                   const u16* __restrict__ projw_b,
                   const float* __restrict__ projlb, const float* __restrict__ projb,
                   const float* __restrict__ gatew, const float* __restrict__ gatelb,
                   const float* __restrict__ gateb,
                   u16* __restrict__ outX)
{
    __shared__ u16   nvA[64][264];     // [k-row][d], pad 256->264
    __shared__ __align__(8) int sconn[100];
    __shared__ float maskv[64];
    __shared__ float sagg[256];
    __shared__ float sred4[4];
    __shared__ float scnt;

    const int bid = blockIdx.x;
    const int* __restrict__ conn;
    const int* __restrict__ sel;
    int b, side, row_off;
    if (bid < 8192) {
        side = bid >> 12; b = bid & 4095;
        conn = side ? q_r1 : q_l1; sel = query; row_off = 0;
    } else {
        const int i = bid - 8192;
        side = i / 5; b = i - side * 5;
        conn = side ? s_r1 : s_l1; sel = support; row_off = 4096;
    }
    const int col_off = side * 256;

    const int t = threadIdx.x;
    const int w = t >> 6, lane = t & 63, quad = lane >> 4, cc = lane & 15;

    if (t < 100) sconn[t] = conn[b * 100 + t];
    const int sid = sel[b * 2 + side];
    const float selfv = emb[(size_t)sid * 256 + t];   // f32 self row (accuracy)
    __syncthreads();

    if (BF16E) {
        // ---- full-batch prefetch: wave w owns k = w + 4*kk ----
        const int nslots = (w < 2) ? 13 : 12;          // wave-uniform
        uint2 ra[13], re[13];
#pragma unroll
        for (int kk = 0; kk < 13; kk++) {
            if (kk < nslots) {
                const int k = w + kk * 4;
                const int2 id = *(const int2*)&sconn[2 * k];
                ra[kk] = *(const uint2*)(embb + (size_t)id.x * 256 + lane * 4);
                re[kk] = *(const uint2*)(embb + (size_t)id.y * 256 + lane * 4);
            }
        }
        // independent work hides under the in-flight loads
        float cnt = 0.f;
        for (int k = 0; k < 50; k++) if (sconn[2 * k] != PAD_IDX) cnt += 1.f;
        if (t < 64) maskv[t] = (t < 50 && sconn[2 * t] != PAD_IDX) ? 1.f : 0.f;
        for (int k = 50; k < 64; k++) nvA[k][t] = 0;
        if (t == 0) scnt = cnt;

#pragma unroll
        for (int kk = 0; kk < 13; kk++) {
            if (kk < nslots) {
                const int k = w + kk * 4;
                u16 o[4];
                o[0] = f2bf(bf2f((u16)(ra[kk].x & 0xffff)) * bf2f((u16)(re[kk].x & 0xffff)));
                o[1] = f2bf(bf2f((u16)(ra[kk].x >> 16))    * bf2f((u16)(re[kk].x >> 16)));
                o[2] = f2bf(bf2f((u16)(ra[kk].y & 0xffff)) * bf2f((u16)(re[kk].y & 0xffff)));
                o[3] = f2bf(bf2f((u16)(ra[kk].y >> 16))    * bf2f((u16)(re[kk].y >> 16)));
                *(uint2*)&nvA[k][lane * 4] = *(uint2*)o;
            }
        }
    } else {
        // f32 fallback: float4 rows, 1-deep prefetch
        float cnt = 0.f;
        for (int k = 0; k < 50; k++) if (sconn[2 * k] != PAD_IDX) cnt += 1.f;
        if (t < 64) maskv[t] = (t < 50 && sconn[2 * t] != PAD_IDX) ? 1.f : 0.f;
        for (int k = 50; k < 64; k++) nvA[k][t] = 0;
        if (t == 0) scnt = cnt;

        int k = w;
        float4 rra, rre;
        {
            const int rel = sconn[2 * k], ent = sconn[2 * k + 1];
            rra = *(const float4*)(emb + (size_t)rel * 256 + lane * 4);
            rre = *(const float4*)(emb + (size_t)ent * 256 + lane * 4);
        }
        while (true) {
            const int kn = k + 4;
            float4 na, ne;
            if (kn < 50) {
                const int rel = sconn[2 * kn], ent = sconn[2 * kn + 1];
                na = *(const float4*)(emb + (size_t)rel * 256 + lane * 4);
                ne = *(const float4*)(emb + (size_t)ent * 256 + lane * 4);
            }
            u16 o[4] = { f2bf(rra.x * rre.x), f2bf(rra.y * rre.y),
                         f2bf(rra.z * rre.z), f2bf(rra.w * rre.w) };
            *(uint2*)&nvA[k][lane * 4] = *(uint2*)o;
            if (kn >= 50) break;
            rra = na; rre = ne; k = kn;
        }
    }
    __syncthreads();
    const float cnt = scnt;

    f32x4 acc[4][4];
#pragma unroll
    for (int mt = 0; mt < 4; mt++)
#pragma unroll
        for (int nt = 0; nt < 4; nt++) acc[mt][nt] = (f32x4){0.f, 0.f, 0.f, 0.f};

    for (int k0 = 0; k0 < 256; k0 += 32) {
        bf16x8 a[4];
#pragma unroll
        for (int mt = 0; mt < 4; mt++)
            a[mt] = *(const bf16x8*)&nvA[mt * 16 + cc][k0 + quad * 8];
#pragma unroll
        for (int nt = 0; nt < 4; nt++) {
            const int e = (w * 4 + nt) * 16 + cc;
            bf16x8 bv = *(const bf16x8*)(projw_b + (size_t)e * 256 + k0 + quad * 8);
#pragma unroll
            for (int mt = 0; mt < 4; mt++)
                acc[mt][nt] = __builtin_amdgcn_mfma_f32_16x16x32_bf16(a[mt], bv, acc[mt][nt], 0, 0, 0);
        }
    }

    float pbv[4], cs[4] = {0.f, 0.f, 0.f, 0.f};
#pragma unroll
    for (int nt = 0; nt < 4; nt++) {
        const int e = (w * 4 + nt) * 16 + cc;
        pbv[nt] = projlb[e] + projb[e];
    }
#pragma unroll
    for (int mt = 0; mt < 4; mt++)
#pragma unroll
        for (int r = 0; r < 4; r++) {
            const float mk = maskv[mt * 16 + quad * 4 + r];
#pragma unroll
            for (int nt = 0; nt < 4; nt++) {
                float v = acc[mt][nt][r] + pbv[nt];
                v = v > 0.f ? v : 0.01f * v;     // leaky_relu(0.01)
                cs[nt] += mk * v;
            }
        }
#pragma unroll
    for (int nt = 0; nt < 4; nt++) {
        cs[nt] += __shfl_xor(cs[nt], 16);
        cs[nt] += __shfl_xor(cs[nt], 32);
    }
    if (quad == 0) {
#pragma unroll
        for (int nt = 0; nt < 4; nt++) sagg[(w * 4 + nt) * 16 + cc] = cs[nt];
    }
    __syncthreads();

    const float agg = sagg[t] / (cnt + 1e-9f);
    // gate dot: wave shuffle reduce (2 barriers total)
    float gv = selfv * gatew[t] + agg * gatew[256 + t];
#pragma unroll
    for (int off = 32; off > 0; off >>= 1) gv += __shfl_xor(gv, off);
    if (lane == 0) sred4[w] = gv;
    __syncthreads();
    const float sgate = sigm(sred4[0] + sred4[1] + sred4[2] + sred4[3]
                             + gatelb[0] + gateb[0]);
    outX[(size_t)(row_off + b) * 512 + col_off + t] = f2bf(tanhf(selfv + sgate * agg));
}

// ---------- generic bf16 MFMA GEMM, DMA-staged (global_load_lds width 16) ----------
// Linear LDS [128][32] (no pad): m97/m98 show gload_lds + linear beats padded
// reg-staging despite read-bank conflicts (m151: 874 vs 646 TF). Per k-step,
// wave w issues 2 A + 2 B DMA loads (chunk = w*2+i covers 16 rows x 64B).
// Rows gm>=M read in-workspace garbage -> only feed dead (unwritten) C rows.
__global__ __launch_bounds__(256)
void gemm_bf16(const u16* __restrict__ A, int lda, const u16* __restrict__ B, int ldb,
               u16* __restrict__ C, int ldc, int M, int N, int K,
               const float* __restrict__ bias, const u16* __restrict__ resid, int ldr, int act)
{
    __shared__ u16 AsL[128 * 32];
    __shared__ u16 BsL[128 * 32];

    const int t = threadIdx.x;
    const int m0 = blockIdx.y * 128, n0 = blockIdx.x * 128;
    const int w = t >> 6, lane = t & 63, quad = lane >> 4, cc = lane & 15;
    const int wm = w >> 1, wn = w & 1;
    const int srow = lane >> 2, sseg = lane & 3;   // DMA source mapping

    f32x4 acc[4][4];
#pragma unroll
    for (int mt = 0; mt < 4; mt++)
#pragma unroll
        for (int nt = 0; nt < 4; nt++) acc[mt][nt] = (f32x4){0.f, 0.f, 0.f, 0.f};

    for (int k0 = 0; k0 < K; k0 += 32) {
#pragma unroll
        for (int i = 0; i < 2; i++) {
            const int chunk = w * 2 + i;                 // 0..7
            const int row = chunk * 16 + srow;           // 0..127
            gload16(A + (size_t)(m0 + row) * lda + k0 + sseg * 8, &AsL[chunk * 512]);
            gload16(B + (size_t)(n0 + row) * ldb + k0 + sseg * 8, &BsL[chunk * 512]);
        }
        __syncthreads();

        bf16x8 af[4], bfr[4];
#pragma unroll
        for (int mt = 0; mt < 4; mt++)
            af[mt] = *(const bf16x8*)&AsL[(wm * 64 + mt * 16 + cc) * 32 + quad * 8];
#pragma unroll
        for (int nt = 0; nt < 4; nt++)
            bfr[nt] = *(const bf16x8*)&BsL[(wn * 64 + nt * 16 + cc) * 32 + quad * 8];
#pragma unroll
        for (int mt = 0; mt < 4; mt++)
#pragma unroll
            for (int nt = 0; nt < 4; nt++)
                acc[mt][nt] = __builtin_amdgcn_mfma_f32_16x16x32_bf16(af[mt], bfr[nt], acc[mt][nt], 0, 0, 0);
        __syncthreads();
    }

#pragma unroll
    for (int mt = 0; mt < 4; mt++)
#pragma unroll
        for (int r = 0; r < 4; r++) {
            const int gm = m0 + wm * 64 + mt * 16 + quad * 4 + r;
            if (gm >= M) continue;
#pragma unroll
            for (int nt = 0; nt < 4; nt++) {
                const int gn = n0 + wn * 64 + nt * 16 + cc;
                if (gn >= N) continue;
                float x = acc[mt][nt][r];
                if (bias)  x += bias[gn];
                if (resid) x += bf2f(resid[(size_t)gm * ldr + gn]);
                if (act == 1) x = x > 0.f ? x : 0.f;
                C[(size_t)gm * ldc + gn] = f2bf(x);
            }
        }
}

// ---------- LSTM step, DEAD-UNIT-HALVED, DMA-staged, fused final dot ----------
// N = 2048 live gate rows (units j<512), grid (16,32), rows exact (no OOB).
// a1mode: 0=none, 1=store A1 (raw ENC@Wih acc), 2=load A1 and add.
// last: fuse out[gm] += sum_j hv*sg[j] (quad shuffle + 1 atomic per 16 lanes).
__global__ __launch_bounds__(256)
void lstm_mfma(const u16* __restrict__ ENCb, const u16* __restrict__ hin,
               const u16* __restrict__ Wp, const float* __restrict__ fb,
               float* __restrict__ cst, u16* __restrict__ houtb,
               const float* __restrict__ sgv, float* __restrict__ outv,
               u16* __restrict__ A1, int step1, int kstart, int kend, int a1mode, int last)
{
    __shared__ u16 AsL[128 * 32];
    __shared__ u16 BsL[128 * 32];

    const int t = threadIdx.x;
    const int m0 = blockIdx.y * 128, n0 = blockIdx.x * 128;
    const int w = t >> 6, lane = t & 63, quad = lane >> 4, cc = lane & 15;
    const int wm = w >> 1, wn = w & 1;
    const int srow = lane >> 2, sseg = lane & 3;

    f32x4 acc[4][4];
#pragma unroll
    for (int mt = 0; mt < 4; mt++)
#pragma unroll
        for (int nt = 0; nt < 4; nt++) acc[mt][nt] = (f32x4){0.f, 0.f, 0.f, 0.f};

    for (int k0 = kstart; k0 < kend; k0 += 32) {
        const u16* Aptr = (k0 < 512) ? ENCb : hin;
        const int kk = (k0 < 512) ? k0 : (k0 - 512);
#pragma unroll
        for (int i = 0; i < 2; i++) {
            const int chunk = w * 2 + i;
            const int row = chunk * 16 + srow;
            gload16(Aptr + (size_t)(m0 + row) * 512 + kk + sseg * 8, &AsL[chunk * 512]);
            gload16(Wp + (size_t)(n0 + row) * 1024 + k0 + sseg * 8, &BsL[chunk * 512]);
        }
        __syncthreads();

        bf16x8 af[4], bfr[4];
#pragma unroll
        for (int mt = 0; mt < 4; mt++)
            af[mt] = *(const bf16x8*)&AsL[(wm * 64 + mt * 16 + cc) * 32 + quad * 8];
#pragma unroll
        for (int nt = 0; nt < 4; nt++)
            bfr[nt] = *(const bf16x8*)&BsL[(wn * 64 + nt * 16 + cc) * 32 + quad * 8];
#pragma unroll
        for (int mt = 0; mt < 4; mt++)
#pragma unroll
            for (int nt = 0; nt < 4; nt++)
                acc[mt][nt] = __builtin_amdgcn_mfma_f32_16x16x32_bf16(af[mt], bfr[nt], acc[mt][nt], 0, 0, 0);
        __syncthreads();
    }

    // epilogue: lane owns gates (i,f,g,o) of unit j<512 for 16 rows
    const int j = blockIdx.x * 32 + wn * 16 + cc;            // 0..511
    const float fbi = fb[n0 + wn * 64 +  0 + cc];
    const float fbf = fb[n0 + wn * 64 + 16 + cc];
    const float fbg = fb[n0 + wn * 64 + 32 + cc];
    const float fbo = fb[n0 + wn * 64 + 48 + cc];
    const float sgj = last ? sgv[j] : 0.f;

#pragma unroll
    for (int mt = 0; mt < 4; mt++)
#pragma unroll
        for (int r = 0; r < 4; r++) {
            const int gm = m0 + wm * 64 + mt * 16 + quad * 4 + r;
            float gi = acc[mt][0][r], gf = acc[mt][1][r];
            float gg = acc[mt][2][r], go = acc[mt][3][r];
            const size_t a1idx = (((size_t)blockIdx.x * 4096 + gm) * 128 + wn * 64 + cc * 4);
            if (a1mode == 1) {
                u16 o[4] = { f2bf(gi), f2bf(gf), f2bf(gg), f2bf(go) };
                *(uint2*)(A1 + a1idx) = *(uint2*)o;
            } else if (a1mode == 2) {
                uint2 v = *(const uint2*)(A1 + a1idx);
                gi += bf2f((u16)(v.x & 0xffff)); gf += bf2f((u16)(v.x >> 16));
                gg += bf2f((u16)(v.y & 0xffff)); go += bf2f((u16)(v.y >> 16));
            }
            gi += fbi; gf += fbf; gg += fbg; go += fbo;
            const float c0 = step1 ? 0.f : cst[(size_t)gm * 512 + j];
            const float cn = sigm(gf) * c0 + sigm(gi) * tanhf(gg);
            const float hv = bf2f(ENCb[(size_t)gm * 512 + j]) + sigm(go) * tanhf(cn);
            if (last) {
                float contrib = hv * sgj;
                contrib += __shfl_xor(contrib, 1);
                contrib += __shfl_xor(contrib, 2);
                contrib += __shfl_xor(contrib, 4);
                contrib += __shfl_xor(contrib, 8);
                if (cc == 0) atomicAdd(&outv[gm], contrib);
            } else {
                cst[(size_t)gm * 512 + j] = cn;
                houtb[(size_t)gm * 512 + j] = f2bf(hv);
            }
        }
}

// ---------- row LayerNorm (wave-shuffle stats: 2 barriers) ----------
__global__ __launch_bounds__(256)
void ln_kernel(u16* __restrict__ X, const float* __restrict__ g, const float* __restrict__ b,
               float* __restrict__ supf)
{
    const int r = blockIdx.x, t = threadIdx.x;
    const int w = t >> 6, lane = t & 63;
    u16* row = X + (size_t)r * 512;
    const float x0 = bf2f(row[t]), x1 = bf2f(row[t + 256]);

    __shared__ float sr[8];
    float s = x0 + x1;
#pragma unroll
    for (int off = 32; off > 0; off >>= 1) s += __shfl_xor(s, off);
    if (lane == 0) sr[w] = s;
    __syncthreads();
    const float mu = (sr[0] + sr[1] + sr[2] + sr[3]) / 512.f;
    const float d0 = x0 - mu, d1 = x1 - mu;
    float s2 = d0 * d0 + d1 * d1;
#pragma unroll
    for (int off = 32; off > 0; off >>= 1) s2 += __shfl_xor(s2, off);
    if (lane == 0) sr[4 + w] = s2;
    __syncthreads();
    const float inv = 1.0f / sqrtf((sr[4] + sr[5] + sr[6] + sr[7]) / 512.f + 1e-5f);
    const float y0 = g[t] * d0 * inv + b[t];
    const float y1 = g[t + 256] * d1 * inv + b[t + 256];
    row[t]       = f2bf(y0);
    row[t + 256] = f2bf(y1);
    if (r >= 4096) {
        supf[(size_t)(r - 4096) * 512 + t]       = y0;
        supf[(size_t)(r - 4096) * 512 + t + 256] = y1;
    }
}

// ---------- Wp build (gate-to-nt permutation, live units only: n<2048) ----------
__global__ __launch_bounds__(256)
void wp_build(const float* __restrict__ wih, const float* __restrict__ whh,
              const float* __restrict__ bih, const float* __restrict__ bhh,
              u16* __restrict__ Wp, float* __restrict__ fb0p)
{
    const int n = blockIdx.x, t = threadIdx.x;
    const int j = (n >> 7) * 32 + ((n >> 6) & 1) * 16 + (n & 15);   // 0..511
    const int gate = (n >> 4) & 3;
    const int r = gate * 1024 + j;
    const int k = t * 4;
    float4 v;
    if (k < 512) v = *(const float4*)(wih + (size_t)r * 512 + k);
    else         v = *(const float4*)(whh + (size_t)r * 1024 + (k - 512));
    u16 o[4] = { f2bf(v.x), f2bf(v.y), f2bf(v.z), f2bf(v.w) };
    *(uint2*)(Wp + (size_t)n * 1024 + k) = *(uint2*)o;
    if (t == 0) fb0p[n] = bih[r] + bhh[r];
}

// ---------- support_g + fb1p: wave-per-output matvec (coalesced whh reads) ----------
// Old version: each thread ran a 512-deep serial fma chain with 4KB-strided
// whh reads (uncoalesced). Now: 64 blocks x 32 outputs; lanes split the dot as
// jx = u*64+lane (whh reads coalesced 256B/instr, ssg LDS reads conflict-free),
// 6-shuffle wave reduce.
__global__ __launch_bounds__(256)
void sg_cvec(const float* __restrict__ supf, const float* __restrict__ whh,
             const float* __restrict__ fb0p, float* __restrict__ sg, float* __restrict__ fb1p)
{
    __shared__ float ssg[512];
    const int t = threadIdx.x;
    const int w = t >> 6, lane = t & 63;
#pragma unroll
    for (int rep = 0; rep < 2; rep++) {
        const int jj = t + rep * 256;
        float v = 0.f;
#pragma unroll
        for (int i = 0; i < 5; i++) v += supf[(size_t)i * 512 + jj];
        v *= 0.2f;
        ssg[jj] = v;
        if (blockIdx.x == 0) sg[jj] = v;
    }
    __syncthreads();
#pragma unroll
    for (int o = 0; o < 8; o++) {
        const int n = blockIdx.x * 32 + w * 8 + o;   // 0..2047
        const int r = ((n >> 4) & 3) * 1024 + (n >> 7) * 32 + ((n >> 6) & 1) * 16 + (n & 15);
        const float* wr = whh + (size_t)r * 1024 + 512;
        float a = 0.f;
#pragma unroll
        for (int u = 0; u < 8; u++) a = fmaf(ssg[u * 64 + lane], wr[u * 64 + lane], a);
#pragma unroll
        for (int off = 32; off > 0; off >>= 1) a += __shfl_xor(a, off);
        if (lane == 0) fb1p[n] = fb0p[n] + a;
    }
}

// ---------- launcher ----------
extern "C" void kernel_launch(void* const* d_in, const int* in_sizes, int n_in,
                              void* d_out, int out_size, void* d_ws, size_t ws_size,
                              hipStream_t stream)
{
    (void)in_sizes; (void)n_in; (void)out_size;
    const int* query     = (const int*)d_in[0];
    const int* support   = (const int*)d_in[1];
    const int* q_l1      = (const int*)d_in[2];
    const int* q_r1      = (const int*)d_in[3];
    const int* s_l1      = (const int*)d_in[4];
    const int* s_r1      = (const int*)d_in[5];
    const float* emb     = (const float*)d_in[6];
    const float* projw   = (const float*)d_in[7];
    const float* projlb  = (const float*)d_in[8];
    const float* projb   = (const float*)d_in[9];
    const float* gatew   = (const float*)d_in[10];
    const float* gatelb  = (const float*)d_in[11];
    const float* gateb   = (const float*)d_in[12];
    const float* sew1    = (const float*)d_in[13];
    const float* seb1    = (const float*)d_in[14];
    const float* sew2    = (const float*)d_in[15];
    const float* seb2    = (const float*)d_in[16];
    const float* lng     = (const float*)d_in[17];
    const float* lnb     = (const float*)d_in[18];
    const float* wih     = (const float*)d_in[19];
    const float* whh     = (const float*)d_in[20];
    const float* bih     = (const float*)d_in[21];
    const float* bhh     = (const float*)d_in[22];

    // ---- workspace layout (float offsets) ----
    float* base   = (float*)d_ws;
    float* sg     = base;                        // 512
    float* fb0p   = base + 512;                  // 2048 used (4096 reserved)
    float* fb1p   = base + 4608;                 // 2048 used
    float* supf   = base + 8704;                 // 5*512
    u16*   projwb = (u16*)(base + 11264);        // 256*256 bf16
    u16*   sew1b  = (u16*)(base + 44032);        // 1024*512 bf16
    u16*   sew2b  = (u16*)(base + 306176);       // 512*1024 bf16
    u16*   Wp     = (u16*)(base + 568320);       // 2048*1024 bf16 (perm, live units)
    u16*   X      = (u16*)(base + 2665472);      // [4104,512]  bf16
    u16*   ENCb   = (u16*)(base + 3716096);      // [4104,512]  bf16
    u16*   hb0    = (u16*)(base + 4766720);      // [4096,512]  bf16
    u16*   hb1    = (u16*)(base + 5815296);      // [4096,512]  bf16
    float* cst    = base + 8961024;              // [4096,512]  f32 (overlays Hb region)
    u16*   Hb     = (u16*)(base + 8961024);      // [4104,1024] bf16 (dead after GEMM2)
    // tiered region: embb (bf16 emb table) and/or A1
    u16*   embb   = (u16*)(base + 13155328);     // [100001,256] bf16 = 51.2 MB
    u16*   A1_hi  = (u16*)(base + 25955456);     // behind embb: 16*4096*128 bf16 = 16.8 MB
    u16*   A1_lo  = (u16*)(base + 13155328);     // legacy position (no embb)

    const size_t NEEDED      = 13155328ull * 4ull;                    //  52.6 MB
    const size_t NEEDED_A1   = (13155328ull +  4194304ull) * 4ull;    //  69.4 MB
    const size_t NEEDED_EMBB = (13155328ull + 12800128ull) * 4ull;    // 103.8 MB
    const size_t NEEDED_ALL  = (25955456ull +  4194304ull) * 4ull;    // 120.6 MB
    if (ws_size < NEEDED) {
        signal_fail<<<16, 256, 0, stream>>>((float*)d_out);
        return;
    }
    const bool use_embb = (ws_size >= NEEDED_EMBB);
    u16* A1 = nullptr;
    bool use_a1 = false;
    if (ws_size >= NEEDED_ALL)                    { use_a1 = true; A1 = A1_hi; }
    else if (!use_embb && ws_size >= NEEDED_A1)   { use_a1 = true; A1 = A1_lo; }

    // weight conversions (run every iteration — harness re-poisons workspace)
    hipMemsetAsync(d_out, 0, 4096 * sizeof(float), stream);
    if (use_embb)
        conv_bf16<<<2048, 256, 0, stream>>>(emb, embb, 25600256);   // 100001*256
    conv3_bf16<<<1088, 256, 0, stream>>>(projw, projwb, sew1, sew1b, sew2, sew2b);
    wp_build<<<2048, 256, 0, stream>>>(wih, whh, bih, bhh, Wp, fb0p);

    // Part A: neighbor encoders -> X (bf16); query+support merged, one side/block
    if (use_embb)
        neighbor_mfma<true><<<8202, 256, 0, stream>>>(
            q_l1, q_r1, s_l1, s_r1, query, support, emb, embb, projwb,
            projlb, projb, gatew, gatelb, gateb, X);
    else
        neighbor_mfma<false><<<8202, 256, 0, stream>>>(
            q_l1, q_r1, s_l1, s_r1, query, support, emb, nullptr, projwb,
            projlb, projb, gatew, gatelb, gateb, X);

    // Part B: support encoder (MFMA, DMA-staged)
    gemm_bf16<<<dim3(8, 33), 256, 0, stream>>>(
        X, 512, sew1b, 512, Hb, 1024, 4101, 1024, 512, seb1, nullptr, 0, 1);
    gemm_bf16<<<dim3(4, 33), 256, 0, stream>>>(
        Hb, 1024, sew2b, 1024, ENCb, 512, 4101, 512, 1024, seb2, X, 512, 0);
    ln_kernel<<<4101, 256, 0, stream>>>(ENCb, lng, lnb, supf);

    sg_cvec<<<64, 256, 0, stream>>>(supf, whh, fb0p, sg, fb1p);

    // LSTM: N=2048 (dead units eliminated); DMA-staged; step 4 fuses final dot
    float* outv = (float*)d_out;
    if (use_a1) {
        lstm_mfma<<<dim3(16, 32), 256, 0, stream>>>(ENCb, hb0, Wp, fb0p, cst, hb0, sg, outv, A1, 1, 0, 512, 1, 0);
        lstm_mfma<<<dim3(16, 32), 256, 0, stream>>>(ENCb, hb0, Wp, fb1p, cst, hb1, sg, outv, A1, 0, 512, 1024, 2, 0);
        lstm_mfma<<<dim3(16, 32), 256, 0, stream>>>(ENCb, hb1, Wp, fb1p, cst, hb0, sg, outv, A1, 0, 512, 1024, 2, 0);
        lstm_mfma<<<dim3(16, 32), 256, 0, stream>>>(ENCb, hb0, Wp, fb1p, cst, hb1, sg, outv, A1, 0, 512, 1024, 2, 1);
    } else {
        lstm_mfma<<<dim3(16, 32), 256, 0, stream>>>(ENCb, hb0, Wp, fb0p, cst, hb0, sg, outv, nullptr, 1, 0, 512, 0, 0);
        lstm_mfma<<<dim3(16, 32), 256, 0, stream>>>(ENCb, hb0, Wp, fb1p, cst, hb1, sg, outv, nullptr, 0, 0, 1024, 0, 0);
        lstm_mfma<<<dim3(16, 32), 256, 0, stream>>>(ENCb, hb1, Wp, fb1p, cst, hb0, sg, outv, nullptr, 0, 0, 1024, 0, 0);
        lstm_mfma<<<dim3(16, 32), 256, 0, stream>>>(ENCb, hb0, Wp, fb1p, cst, hb1, sg, outv, nullptr, 0, 0, 1024, 0, 1);
    }
}

// Round 13
// 613.742 us; speedup vs baseline: 1.5299x; 1.0022x over previous
//
#include <hip/hip_runtime.h>
#include <hip/hip_bf16.h>

typedef unsigned short u16;
typedef unsigned int   u32;
typedef __attribute__((ext_vector_type(8))) short bf16x8;   // 8 bf16 = 4 VGPRs
typedef __attribute__((ext_vector_type(4))) float f32x4;

// ---------- helpers ----------
__device__ __forceinline__ float bf2f(u16 u) {
    union { u32 i; float f; } v; v.i = ((u32)u) << 16; return v.f;
}
__device__ __forceinline__ u16 f2bf(float f) {
    __hip_bfloat16 h = __float2bfloat16(f);
    return *reinterpret_cast<u16*>(&h);
}
__device__ __forceinline__ float sigm(float x) { return 1.0f / (1.0f + expf(-x)); }

// async global->LDS DMA, 16B per lane: LDS dest = wave-uniform base + lane*16,
// global source per-lane. Completion tracked by vmcnt (drained at __syncthreads).
__device__ __forceinline__ void gload16(const u16* g, u16* l) {
    __builtin_amdgcn_global_load_lds(
        (const __attribute__((address_space(1))) u32*)(const void*)g,
        (__attribute__((address_space(3))) u32*)(void*)l, 16, 0, 0);
}

#define PAD_IDX 100000

// ---------- workspace-too-small sentinel ----------
__global__ __launch_bounds__(256)
void signal_fail(float* out) {
    int i = blockIdx.x * 256 + threadIdx.x;
    if (i < 4096) out[i] = 12345.0f;
}

// ---------- f32 -> bf16 conversion ----------
// (R9: harness re-poisons workspace between iterations — weight prep cannot be
//  cached. R10: persistent LSTM state in registers spills — use L2 buffers.)
__global__ __launch_bounds__(256)
void conv_bf16(const float* __restrict__ in, u16* __restrict__ out, long n) {
    long i = ((long)blockIdx.x * 256 + threadIdx.x) * 4;
    const long stride = (long)gridDim.x * 256 * 4;
    for (; i < n; i += stride) {
        float4 v = *(const float4*)(in + i);
        u16 o[4] = { f2bf(v.x), f2bf(v.y), f2bf(v.z), f2bf(v.w) };
        *(uint2*)(out + i) = *(uint2*)o;
    }
}

// ---------- fused prep: projw|sew1|sew2 conversions + Wp build (one launch) ----------
// bx<64: projw, <576: sew1, <1088: sew2, <3136: wp_build row (n = bx-1088).
__global__ __launch_bounds__(256)
void prep_kernel(const float* __restrict__ projw, u16* __restrict__ projwb,
                 const float* __restrict__ sew1, u16* __restrict__ sew1b,
                 const float* __restrict__ sew2, u16* __restrict__ sew2b,
                 const float* __restrict__ wih, const float* __restrict__ whh,
                 const float* __restrict__ bih, const float* __restrict__ bhh,
                 u16* __restrict__ Wp, float* __restrict__ fb0p)
{
    const int bx = blockIdx.x, t = threadIdx.x;
    if (bx < 1088) {
        const float* in; u16* out; long n, b0;
        if (bx < 64)        { in = projw; out = projwb; n = 65536;  b0 = bx; }
        else if (bx < 576)  { in = sew1;  out = sew1b;  n = 524288; b0 = bx - 64; }
        else                { in = sew2;  out = sew2b;  n = 524288; b0 = bx - 576; }
        long i = (b0 * 256 + t) * 4;
        if (i < n) {
            float4 v = *(const float4*)(in + i);
            u16 o[4] = { f2bf(v.x), f2bf(v.y), f2bf(v.z), f2bf(v.w) };
            *(uint2*)(out + i) = *(uint2*)o;
        }
    } else {
        const int n = bx - 1088;                                      // 0..2047
        const int j = (n >> 7) * 32 + ((n >> 6) & 1) * 16 + (n & 15); // 0..511
        const int gate = (n >> 4) & 3;
        const int r = gate * 1024 + j;
        const int k = t * 4;
        float4 v;
        if (k < 512) v = *(const float4*)(wih + (size_t)r * 512 + k);
        else         v = *(const float4*)(whh + (size_t)r * 1024 + (k - 512));
        u16 o[4] = { f2bf(v.x), f2bf(v.y), f2bf(v.z), f2bf(v.w) };
        *(uint2*)(Wp + (size_t)n * 1024 + k) = *(uint2*)o;
        if (t == 0) fb0p[n] = bih[r] + bhh[r];
    }
}

// ---------- Part A: neighbor encoder (R6-exact, measured plateau 205us) ----------
// Merged grid: blocks [0,8192) = query, [8192,8202) = support. Full-batch
// 26-load gather/wave. Random 512B-row gather of 51MB table plateaus ~1 TB/s
// HBM-side (FETCH 198MB/dispatch ≈ dispatch time at achieved random BW);
// forced-occupancy spills (R7). No __launch_bounds__ min-wave hints here.
template<bool BF16E>
__global__ __launch_bounds__(256)
void neighbor_mfma(const int* __restrict__ q_l1, const int* __restrict__ q_r1,
                   const int* __restrict__ s_l1, const int* __restrict__ s_r1,
                   const int* __restrict__ query, const int* __restrict__ support,
                   const float* __restrict__ emb, const u16* __restrict__ embb,
                   const u16* __restrict__ projw_b,
                   const float* __restrict__ projlb, const float* __restrict__ projb,
                   const float* __restrict__ gatew, const float* __restrict__ gatelb,
                   const float* __restrict__ gateb,
                   u16* __restrict__ outX)
{
    __shared__ u16   nvA[64][264];     // [k-row][d], pad 256->264
    __shared__ __align__(8) int sconn[100];
    __shared__ float maskv[64];
    __shared__ float sagg[256];
    __shared__ float sred4[4];
    __shared__ float scnt;

    const int bid = blockIdx.x;
    const int* __restrict__ conn;
    const int* __restrict__ sel;
    int b, side, row_off;
    if (bid < 8192) {
        side = bid >> 12; b = bid & 4095;
        conn = side ? q_r1 : q_l1; sel = query; row_off = 0;
    } else {
        const int i = bid - 8192;
        side = i / 5; b = i - side * 5;
        conn = side ? s_r1 : s_l1; sel = support; row_off = 4096;
    }
    const int col_off = side * 256;

    const int t = threadIdx.x;
    const int w = t >> 6, lane = t & 63, quad = lane >> 4, cc = lane & 15;

    if (t < 100) sconn[t] = conn[b * 100 + t];
    const int sid = sel[b * 2 + side];
    const float selfv = emb[(size_t)sid * 256 + t];   // f32 self row (accuracy)
    __syncthreads();

    if (BF16E) {
        // ---- full-batch prefetch: wave w owns k = w + 4*kk ----
        const int nslots = (w < 2) ? 13 : 12;          // wave-uniform
        uint2 ra[13], re[13];
#pragma unroll
        for (int kk = 0; kk < 13; kk++) {
            if (kk < nslots) {
                const int k = w + kk * 4;
                const int2 id = *(const int2*)&sconn[2 * k];
                ra[kk] = *(const uint2*)(embb + (size_t)id.x * 256 + lane * 4);
                re[kk] = *(const uint2*)(embb + (size_t)id.y * 256 + lane * 4);
            }
        }
        // independent work hides under the in-flight loads
        float cnt = 0.f;
        for (int k = 0; k < 50; k++) if (sconn[2 * k] != PAD_IDX) cnt += 1.f;
        if (t < 64) maskv[t] = (t < 50 && sconn[2 * t] != PAD_IDX) ? 1.f : 0.f;
        for (int k = 50; k < 64; k++) nvA[k][t] = 0;
        if (t == 0) scnt = cnt;

#pragma unroll
        for (int kk = 0; kk < 13; kk++) {
            if (kk < nslots) {
                const int k = w + kk * 4;
                u16 o[4];
                o[0] = f2bf(bf2f((u16)(ra[kk].x & 0xffff)) * bf2f((u16)(re[kk].x & 0xffff)));
                o[1] = f2bf(bf2f((u16)(ra[kk].x >> 16))    * bf2f((u16)(re[kk].x >> 16)));
                o[2] = f2bf(bf2f((u16)(ra[kk].y & 0xffff)) * bf2f((u16)(re[kk].y & 0xffff)));
                o[3] = f2bf(bf2f((u16)(ra[kk].y >> 16))    * bf2f((u16)(re[kk].y >> 16)));
                *(uint2*)&nvA[k][lane * 4] = *(uint2*)o;
            }
        }
    } else {
        // f32 fallback: float4 rows, 1-deep prefetch
        float cnt = 0.f;
        for (int k = 0; k < 50; k++) if (sconn[2 * k] != PAD_IDX) cnt += 1.f;
        if (t < 64) maskv[t] = (t < 50 && sconn[2 * t] != PAD_IDX) ? 1.f : 0.f;
        for (int k = 50; k < 64; k++) nvA[k][t] = 0;
        if (t == 0) scnt = cnt;

        int k = w;
        float4 rra, rre;
        {
            const int rel = sconn[2 * k], ent = sconn[2 * k + 1];
            rra = *(const float4*)(emb + (size_t)rel * 256 + lane * 4);
            rre = *(const float4*)(emb + (size_t)ent * 256 + lane * 4);
        }
        while (true) {
            const int kn = k + 4;
            float4 na, ne;
            if (kn < 50) {
                const int rel = sconn[2 * kn], ent = sconn[2 * kn + 1];
                na = *(const float4*)(emb + (size_t)rel * 256 + lane * 4);
                ne = *(const float4*)(emb + (size_t)ent * 256 + lane * 4);
            }
            u16 o[4] = { f2bf(rra.x * rre.x), f2bf(rra.y * rre.y),
                         f2bf(rra.z * rre.z), f2bf(rra.w * rre.w) };
            *(uint2*)&nvA[k][lane * 4] = *(uint2*)o;
            if (kn >= 50) break;
            rra = na; rre = ne; k = kn;
        }
    }
    __syncthreads();
    const float cnt = scnt;

    f32x4 acc[4][4];
#pragma unroll
    for (int mt = 0; mt < 4; mt++)
#pragma unroll
        for (int nt = 0; nt < 4; nt++) acc[mt][nt] = (f32x4){0.f, 0.f, 0.f, 0.f};

    for (int k0 = 0; k0 < 256; k0 += 32) {
        bf16x8 a[4];
#pragma unroll
        for (int mt = 0; mt < 4; mt++)
            a[mt] = *(const bf16x8*)&nvA[mt * 16 + cc][k0 + quad * 8];
#pragma unroll
        for (int nt = 0; nt < 4; nt++) {
            const int e = (w * 4 + nt) * 16 + cc;
            bf16x8 bv = *(const bf16x8*)(projw_b + (size_t)e * 256 + k0 + quad * 8);
#pragma unroll
            for (int mt = 0; mt < 4; mt++)
                acc[mt][nt] = __builtin_amdgcn_mfma_f32_16x16x32_bf16(a[mt], bv, acc[mt][nt], 0, 0, 0);
        }
    }

    float pbv[4], cs[4] = {0.f, 0.f, 0.f, 0.f};
#pragma unroll
    for (int nt = 0; nt < 4; nt++) {
        const int e = (w * 4 + nt) * 16 + cc;
        pbv[nt] = projlb[e] + projb[e];
    }
#pragma unroll
    for (int mt = 0; mt < 4; mt++)
#pragma unroll
        for (int r = 0; r < 4; r++) {
            const float mk = maskv[mt * 16 + quad * 4 + r];
#pragma unroll
            for (int nt = 0; nt < 4; nt++) {
                float v = acc[mt][nt][r] + pbv[nt];
                v = v > 0.f ? v : 0.01f * v;     // leaky_relu(0.01)
                cs[nt] += mk * v;
            }
        }
#pragma unroll
    for (int nt = 0; nt < 4; nt++) {
        cs[nt] += __shfl_xor(cs[nt], 16);
        cs[nt] += __shfl_xor(cs[nt], 32);
    }
    if (quad == 0) {
#pragma unroll
        for (int nt = 0; nt < 4; nt++) sagg[(w * 4 + nt) * 16 + cc] = cs[nt];
    }
    __syncthreads();

    const float agg = sagg[t] / (cnt + 1e-9f);
    // gate dot: wave shuffle reduce (2 barriers total)
    float gv = selfv * gatew[t] + agg * gatew[256 + t];
#pragma unroll
    for (int off = 32; off > 0; off >>= 1) gv += __shfl_xor(gv, off);
    if (lane == 0) sred4[w] = gv;
    __syncthreads();
    const float sgate = sigm(sred4[0] + sred4[1] + sred4[2] + sred4[3]
                             + gatelb[0] + gateb[0]);
    outX[(size_t)(row_off + b) * 512 + col_off + t] = f2bf(tanhf(selfv + sgate * agg));
}

// ---------- generic bf16 MFMA GEMM, DMA-staged (global_load_lds width 16) ----------
// Linear LDS [128][32] (no pad). Rows gm>=M read in-workspace garbage -> only
// feed dead (unwritten) C rows.
__global__ __launch_bounds__(256)
void gemm_bf16(const u16* __restrict__ A, int lda, const u16* __restrict__ B, int ldb,
               u16* __restrict__ C, int ldc, int M, int N, int K,
               const float* __restrict__ bias, const u16* __restrict__ resid, int ldr, int act)
{
    __shared__ u16 AsL[128 * 32];
    __shared__ u16 BsL[128 * 32];

    const int t = threadIdx.x;
    const int m0 = blockIdx.y * 128, n0 = blockIdx.x * 128;
    const int w = t >> 6, lane = t & 63, quad = lane >> 4, cc = lane & 15;
    const int wm = w >> 1, wn = w & 1;
    const int srow = lane >> 2, sseg = lane & 3;   // DMA source mapping

    f32x4 acc[4][4];
#pragma unroll
    for (int mt = 0; mt < 4; mt++)
#pragma unroll
        for (int nt = 0; nt < 4; nt++) acc[mt][nt] = (f32x4){0.f, 0.f, 0.f, 0.f};

    for (int k0 = 0; k0 < K; k0 += 32) {
#pragma unroll
        for (int i = 0; i < 2; i++) {
            const int chunk = w * 2 + i;                 // 0..7
            const int row = chunk * 16 + srow;           // 0..127
            gload16(A + (size_t)(m0 + row) * lda + k0 + sseg * 8, &AsL[chunk * 512]);
            gload16(B + (size_t)(n0 + row) * ldb + k0 + sseg * 8, &BsL[chunk * 512]);
        }
        __syncthreads();

        bf16x8 af[4], bfr[4];
#pragma unroll
        for (int mt = 0; mt < 4; mt++)
            af[mt] = *(const bf16x8*)&AsL[(wm * 64 + mt * 16 + cc) * 32 + quad * 8];
#pragma unroll
        for (int nt = 0; nt < 4; nt++)
            bfr[nt] = *(const bf16x8*)&BsL[(wn * 64 + nt * 16 + cc) * 32 + quad * 8];
#pragma unroll
        for (int mt = 0; mt < 4; mt++)
#pragma unroll
            for (int nt = 0; nt < 4; nt++)
                acc[mt][nt] = __builtin_amdgcn_mfma_f32_16x16x32_bf16(af[mt], bfr[nt], acc[mt][nt], 0, 0, 0);
        __syncthreads();
    }

#pragma unroll
    for (int mt = 0; mt < 4; mt++)
#pragma unroll
        for (int r = 0; r < 4; r++) {
            const int gm = m0 + wm * 64 + mt * 16 + quad * 4 + r;
            if (gm >= M) continue;
#pragma unroll
            for (int nt = 0; nt < 4; nt++) {
                const int gn = n0 + wn * 64 + nt * 16 + cc;
                if (gn >= N) continue;
                float x = acc[mt][nt][r];
                if (bias)  x += bias[gn];
                if (resid) x += bf2f(resid[(size_t)gm * ldr + gn]);
                if (act == 1) x = x > 0.f ? x : 0.f;
                C[(size_t)gm * ldc + gn] = f2bf(x);
            }
        }
}

// ---------- LSTM step, DEAD-UNIT-HALVED, DMA-staged, A1-cached, fused dot ----------
// N = 2048 live gate rows (units j<512), grid (16,32). A1 = ENC@Wih preacts in
// bf16, split across two dead 8.4MB workspace regions by n-block (blockIdx.x<8
// -> A1a, else A1b; both inside the base 52.6MB envelope, dead after gemm2).
// Steps 2-4 run only K=512..1024 (h part) and add A1 back — the ENC@Wih GEMM
// is computed once, not 4x. R10 lesson: this reuse must be L2-backed, not VGPR.
__global__ __launch_bounds__(256)
void lstm_mfma(const u16* __restrict__ ENCb, const u16* __restrict__ hin,
               const u16* __restrict__ Wp, const float* __restrict__ fb,
               float* __restrict__ cst, u16* __restrict__ houtb,
               const float* __restrict__ sgv, float* __restrict__ outv,
               u16* __restrict__ A1a, u16* __restrict__ A1b,
               int step1, int kstart, int kend, int a1mode, int last)
{
    __shared__ u16 AsL[128 * 32];
    __shared__ u16 BsL[128 * 32];

    const int t = threadIdx.x;
    const int m0 = blockIdx.y * 128, n0 = blockIdx.x * 128;
    const int w = t >> 6, lane = t & 63, quad = lane >> 4, cc = lane & 15;
    const int wm = w >> 1, wn = w & 1;
    const int srow = lane >> 2, sseg = lane & 3;
    u16* A1p = (blockIdx.x < 8) ? A1a : A1b;

    f32x4 acc[4][4];
#pragma unroll
    for (int mt = 0; mt < 4; mt++)
#pragma unroll
        for (int nt = 0; nt < 4; nt++) acc[mt][nt] = (f32x4){0.f, 0.f, 0.f, 0.f};

    for (int k0 = kstart; k0 < kend; k0 += 32) {
        const u16* Aptr = (k0 < 512) ? ENCb : hin;
        const int kk = (k0 < 512) ? k0 : (k0 - 512);
#pragma unroll
        for (int i = 0; i < 2; i++) {
            const int chunk = w * 2 + i;
            const int row = chunk * 16 + srow;
            gload16(Aptr + (size_t)(m0 + row) * 512 + kk + sseg * 8, &AsL[chunk * 512]);
            gload16(Wp + (size_t)(n0 + row) * 1024 + k0 + sseg * 8, &BsL[chunk * 512]);
        }
        __syncthreads();

        bf16x8 af[4], bfr[4];
#pragma unroll
        for (int mt = 0; mt < 4; mt++)
            af[mt] = *(const bf16x8*)&AsL[(wm * 64 + mt * 16 + cc) * 32 + quad * 8];
#pragma unroll
        for (int nt = 0; nt < 4; nt++)
            bfr[nt] = *(const bf16x8*)&BsL[(wn * 64 + nt * 16 + cc) * 32 + quad * 8];
#pragma unroll
        for (int mt = 0; mt < 4; mt++)
#pragma unroll
            for (int nt = 0; nt < 4; nt++)
                acc[mt][nt] = __builtin_amdgcn_mfma_f32_16x16x32_bf16(af[mt], bfr[nt], acc[mt][nt], 0, 0, 0);
        __syncthreads();
    }

    // epilogue: lane owns gates (i,f,g,o) of unit j<512 for 16 rows
    const int j = blockIdx.x * 32 + wn * 16 + cc;            // 0..511
    const float fbi = fb[n0 + wn * 64 +  0 + cc];
    const float fbf = fb[n0 + wn * 64 + 16 + cc];
    const float fbg = fb[n0 + wn * 64 + 32 + cc];
    const float fbo = fb[n0 + wn * 64 + 48 + cc];
    const float sgj = last ? sgv[j] : 0.f;

#pragma unroll
    for (int mt = 0; mt < 4; mt++)
#pragma unroll
        for (int r = 0; r < 4; r++) {
            const int gm = m0 + wm * 64 + mt * 16 + quad * 4 + r;
            float gi = acc[mt][0][r], gf = acc[mt][1][r];
            float gg = acc[mt][2][r], go = acc[mt][3][r];
            const size_t a1idx = ((((size_t)(blockIdx.x & 7)) * 4096 + gm) * 128 + wn * 64 + cc * 4);
            if (a1mode == 1) {
                u16 o[4] = { f2bf(gi), f2bf(gf), f2bf(gg), f2bf(go) };
                *(uint2*)(A1p + a1idx) = *(uint2*)o;
            } else if (a1mode == 2) {
                uint2 v = *(const uint2*)(A1p + a1idx);
                gi += bf2f((u16)(v.x & 0xffff)); gf += bf2f((u16)(v.x >> 16));
                gg += bf2f((u16)(v.y & 0xffff)); go += bf2f((u16)(v.y >> 16));
            }
            gi += fbi; gf += fbf; gg += fbg; go += fbo;
            const float c0 = step1 ? 0.f : cst[(size_t)gm * 512 + j];
            const float cn = sigm(gf) * c0 + sigm(gi) * tanhf(gg);
            const float hv = bf2f(ENCb[(size_t)gm * 512 + j]) + sigm(go) * tanhf(cn);
            if (last) {
                float contrib = hv * sgj;
                contrib += __shfl_xor(contrib, 1);
                contrib += __shfl_xor(contrib, 2);
                contrib += __shfl_xor(contrib, 4);
                contrib += __shfl_xor(contrib, 8);
                if (cc == 0) atomicAdd(&outv[gm], contrib);
            } else {
                cst[(size_t)gm * 512 + j] = cn;
                houtb[(size_t)gm * 512 + j] = f2bf(hv);
            }
        }
}

// ---------- row LayerNorm (wave-shuffle stats: 2 barriers) ----------
__global__ __launch_bounds__(256)
void ln_kernel(u16* __restrict__ X, const float* __restrict__ g, const float* __restrict__ b,
               float* __restrict__ supf)
{
    const int r = blockIdx.x, t = threadIdx.x;
    const int w = t >> 6, lane = t & 63;
    u16* row = X + (size_t)r * 512;
    const float x0 = bf2f(row[t]), x1 = bf2f(row[t + 256]);

    __shared__ float sr[8];
    float s = x0 + x1;
#pragma unroll
    for (int off = 32; off > 0; off >>= 1) s += __shfl_xor(s, off);
    if (lane == 0) sr[w] = s;
    __syncthreads();
    const float mu = (sr[0] + sr[1] + sr[2] + sr[3]) / 512.f;
    const float d0 = x0 - mu, d1 = x1 - mu;
    float s2 = d0 * d0 + d1 * d1;
#pragma unroll
    for (int off = 32; off > 0; off >>= 1) s2 += __shfl_xor(s2, off);
    if (lane == 0) sr[4 + w] = s2;
    __syncthreads();
    const float inv = 1.0f / sqrtf((sr[4] + sr[5] + sr[6] + sr[7]) / 512.f + 1e-5f);
    const float y0 = g[t] * d0 * inv + b[t];
    const float y1 = g[t + 256] * d1 * inv + b[t + 256];
    row[t]       = f2bf(y0);
    row[t + 256] = f2bf(y1);
    if (r >= 4096) {
        supf[(size_t)(r - 4096) * 512 + t]       = y0;
        supf[(size_t)(r - 4096) * 512 + t + 256] = y1;
    }
}

// ---------- support_g + fb1p: wave-per-output matvec (coalesced whh reads) ----------
__global__ __launch_bounds__(256)
void sg_cvec(const float* __restrict__ supf, const float* __restrict__ whh,
             const float* __restrict__ fb0p, float* __restrict__ sg, float* __restrict__ fb1p)
{
    __shared__ float ssg[512];
    const int t = threadIdx.x;
    const int w = t >> 6, lane = t & 63;
#pragma unroll
    for (int rep = 0; rep < 2; rep++) {
        const int jj = t + rep * 256;
        float v = 0.f;
#pragma unroll
        for (int i = 0; i < 5; i++) v += supf[(size_t)i * 512 + jj];
        v *= 0.2f;
        ssg[jj] = v;
        if (blockIdx.x == 0) sg[jj] = v;
    }
    __syncthreads();
#pragma unroll
    for (int o = 0; o < 8; o++) {
        const int n = blockIdx.x * 32 + w * 8 + o;   // 0..2047
        const int r = ((n >> 4) & 3) * 1024 + (n >> 7) * 32 + ((n >> 6) & 1) * 16 + (n & 15);
        const float* wr = whh + (size_t)r * 1024 + 512;
        float a = 0.f;
#pragma unroll
        for (int u = 0; u < 8; u++) a = fmaf(ssg[u * 64 + lane], wr[u * 64 + lane], a);
#pragma unroll
        for (int off = 32; off > 0; off >>= 1) a += __shfl_xor(a, off);
        if (lane == 0) fb1p[n] = fb0p[n] + a;
    }
}

// ---------- launcher ----------
extern "C" void kernel_launch(void* const* d_in, const int* in_sizes, int n_in,
                              void* d_out, int out_size, void* d_ws, size_t ws_size,
                              hipStream_t stream)
{
    (void)in_sizes; (void)n_in; (void)out_size;
    const int* query     = (const int*)d_in[0];
    const int* support   = (const int*)d_in[1];
    const int* q_l1      = (const int*)d_in[2];
    const int* q_r1      = (const int*)d_in[3];
    const int* s_l1      = (const int*)d_in[4];
    const int* s_r1      = (const int*)d_in[5];
    const float* emb     = (const float*)d_in[6];
    const float* projw   = (const float*)d_in[7];
    const float* projlb  = (const float*)d_in[8];
    const float* projb   = (const float*)d_in[9];
    const float* gatew   = (const float*)d_in[10];
    const float* gatelb  = (const float*)d_in[11];
    const float* gateb   = (const float*)d_in[12];
    const float* sew1    = (const float*)d_in[13];
    const float* seb1    = (const float*)d_in[14];
    const float* sew2    = (const float*)d_in[15];
    const float* seb2    = (const float*)d_in[16];
    const float* lng     = (const float*)d_in[17];
    const float* lnb     = (const float*)d_in[18];
    const float* wih     = (const float*)d_in[19];
    const float* whh     = (const float*)d_in[20];
    const float* bih     = (const float*)d_in[21];
    const float* bhh     = (const float*)d_in[22];

    // ---- workspace layout (float offsets) ----
    float* base   = (float*)d_ws;
    float* sg     = base;                        // 512
    float* fb0p   = base + 512;                  // 2048 used (4096 reserved)
    float* fb1p   = base + 4608;                 // 2048 used
    float* supf   = base + 8704;                 // 5*512
    u16*   projwb = (u16*)(base + 11264);        // 256*256 bf16
    u16*   sew1b  = (u16*)(base + 44032);        // 1024*512 bf16
    u16*   sew2b  = (u16*)(base + 306176);       // 512*1024 bf16
    u16*   Wp     = (u16*)(base + 568320);       // 2048*1024 bf16 (perm, live units)
    u16*   X      = (u16*)(base + 2665472);      // [4104,512]  bf16 (dead after gemm2)
    u16*   ENCb   = (u16*)(base + 3716096);      // [4104,512]  bf16
    u16*   hb0    = (u16*)(base + 4766720);      // [4096,512]  bf16
    u16*   hb1    = (u16*)(base + 5815296);      // [4096,512]  bf16
    u16*   A1a    = (u16*)(base + 6863872);      // 8.4MB (old hf slot, unused)
    float* cst    = base + 8961024;              // [4096,512] f32 (lower Hb half)
    u16*   Hb     = (u16*)(base + 8961024);      // [4104,1024] bf16 (dead after gemm2)
    u16*   A1b    = (u16*)(base + 11058176);     // 8.4MB (upper Hb half, dead after gemm2)
    u16*   embb   = (u16*)(base + 13155328);     // [100001,256] bf16 = 51.2 MB

    const size_t NEEDED      = 13155328ull * 4ull;                    //  52.6 MB
    const size_t NEEDED_EMBB = (13155328ull + 12800128ull) * 4ull;    // 103.8 MB
    if (ws_size < NEEDED) {
        signal_fail<<<16, 256, 0, stream>>>((float*)d_out);
        return;
    }
    const bool use_embb = (ws_size >= NEEDED_EMBB);

    // weight conversions (run every iteration — harness re-poisons workspace)
    hipMemsetAsync(d_out, 0, 4096 * sizeof(float), stream);
    if (use_embb)
        conv_bf16<<<2048, 256, 0, stream>>>(emb, embb, 25600256);   // 100001*256
    prep_kernel<<<3136, 256, 0, stream>>>(projw, projwb, sew1, sew1b, sew2, sew2b,
                                          wih, whh, bih, bhh, Wp, fb0p);

    // Part A: neighbor encoders -> X (bf16); query+support merged, one side/block
    if (use_embb)
        neighbor_mfma<true><<<8202, 256, 0, stream>>>(
            q_l1, q_r1, s_l1, s_r1, query, support, emb, embb, projwb,
            projlb, projb, gatew, gatelb, gateb, X);
    else
        neighbor_mfma<false><<<8202, 256, 0, stream>>>(
            q_l1, q_r1, s_l1, s_r1, query, support, emb, nullptr, projwb,
            projlb, projb, gatew, gatelb, gateb, X);

    // Part B: support encoder (MFMA, DMA-staged)
    gemm_bf16<<<dim3(8, 33), 256, 0, stream>>>(
        X, 512, sew1b, 512, Hb, 1024, 4101, 1024, 512, seb1, nullptr, 0, 1);
    gemm_bf16<<<dim3(4, 33), 256, 0, stream>>>(
        Hb, 1024, sew2b, 1024, ENCb, 512, 4101, 512, 1024, seb2, X, 512, 0);
    ln_kernel<<<4101, 256, 0, stream>>>(ENCb, lng, lnb, supf);

    sg_cvec<<<64, 256, 0, stream>>>(supf, whh, fb0p, sg, fb1p);

    // LSTM: A1 cache ALWAYS on (carved from dead workspace regions);
    // steps 2-4 run only the K=512..1024 half + A1 add.
    float* outv = (float*)d_out;
    lstm_mfma<<<dim3(16, 32), 256, 0, stream>>>(ENCb, hb0, Wp, fb0p, cst, hb0, sg, outv, A1a, A1b, 1, 0, 512, 1, 0);
    lstm_mfma<<<dim3(16, 32), 256, 0, stream>>>(ENCb, hb0, Wp, fb1p, cst, hb1, sg, outv, A1a, A1b, 0, 512, 1024, 2, 0);
    lstm_mfma<<<dim3(16, 32), 256, 0, stream>>>(ENCb, hb1, Wp, fb1p, cst, hb0, sg, outv, A1a, A1b, 0, 512, 1024, 2, 0);
    lstm_mfma<<<dim3(16, 32), 256, 0, stream>>>(ENCb, hb0, Wp, fb1p, cst, hb1, sg, outv, A1a, A1b, 0, 512, 1024, 2, 1);
}